// Round 8
// baseline (1266.425 us; speedup 1.0000x reference)
//
#include <hip/hip_runtime.h>
#include <math.h>

#define SEQ 2516
#define CDIM 128

__device__ __forceinline__ float gelu_exact(float x) {
    return x * 0.5f * (1.0f + erff(x * 0.7071067811865475f));
}
__device__ __forceinline__ float fexp2(float x) { return __builtin_amdgcn_exp2f(x); }

// ---------------- concat + LN1(layer0): one wave per row ------------------------
__global__ __launch_bounds__(64) void concat_ln_kernel(
    const float* __restrict__ td, const float* __restrict__ sup,
    const float* __restrict__ g, const float* __restrict__ b,
    float* __restrict__ X, float* __restrict__ H) {
    const int row = blockIdx.x;
    const int t = threadIdx.x;
    float x0, x1;
    if (row < 16) {
        x0 = td[row * 128 + t];
        x1 = td[row * 128 + 64 + t];
    } else {
        int r = row - 16;
        int n = r / 100, p = r - n * 100;
        x0 = sup[n * 12800 + t * 100 + p];
        x1 = sup[n * 12800 + (t + 64) * 100 + p];
    }
    X[row * 128 + t] = x0;
    X[row * 128 + 64 + t] = x1;
    float s = x0 + x1;
    for (int off = 32; off > 0; off >>= 1) s += __shfl_down(s, off);
    float mean = __shfl(s, 0) * (1.f / 128.f);
    float d0 = x0 - mean, d1 = x1 - mean;
    float v = d0 * d0 + d1 * d1;
    for (int off = 32; off > 0; off >>= 1) v += __shfl_down(v, off);
    float var = __shfl(v, 0) * (1.f / 128.f);
    float rstd = rsqrtf(var + 1e-5f);
    H[row * 128 + t]      = d0 * rstd * g[t] + b[t];
    H[row * 128 + 64 + t] = d1 * rstd * g[t + 64] + b[t + 64];
}

// ---------------- skinny GEMM: 8 M-rows x N cols per block ----------------------
template<int N, int RPT, int ACT, bool RES>
__global__ __launch_bounds__(N * 8 / RPT) void sgemm_kernel(
    const float* __restrict__ A, const float* __restrict__ W,
    const float* __restrict__ bias, const float* __restrict__ R,
    float* __restrict__ C, int M, int K) {
    const int t = threadIdx.x;
    const int c = t % N;
    const int grp = __builtin_amdgcn_readfirstlane(t / N);
    const int r0 = blockIdx.x * 8 + grp * RPT;
    float acc[RPT];
    #pragma unroll
    for (int i = 0; i < RPT; ++i) acc[i] = 0.f;
    #pragma unroll 4
    for (int k0 = 0; k0 < K; k0 += 4) {
        float w0 = W[(size_t)(k0 + 0) * N + c];
        float w1 = W[(size_t)(k0 + 1) * N + c];
        float w2 = W[(size_t)(k0 + 2) * N + c];
        float w3 = W[(size_t)(k0 + 3) * N + c];
        #pragma unroll
        for (int i = 0; i < RPT; ++i) {
            float4 a4 = *(const float4*)&A[(size_t)(r0 + i) * K + k0];
            acc[i] = fmaf(a4.x, w0, acc[i]);
            acc[i] = fmaf(a4.y, w1, acc[i]);
            acc[i] = fmaf(a4.z, w2, acc[i]);
            acc[i] = fmaf(a4.w, w3, acc[i]);
        }
    }
    float bv = bias[c];
    #pragma unroll
    for (int i = 0; i < RPT; ++i) {
        int row = r0 + i;
        if (row < M) {
            float v = acc[i] + bv;
            if (ACT == 1) v = gelu_exact(v);
            if (RES) v += R[(size_t)row * N + c];
            C[(size_t)row * N + c] = v;
        }
    }
}

// ------- skinny GEMM N=128 + residual + row-LN epilogue (writes C and H) --------
__global__ __launch_bounds__(512) void sgemm_ln_kernel(
    const float* __restrict__ A, const float* __restrict__ W,
    const float* __restrict__ bias, const float* __restrict__ R,
    float* __restrict__ C, float* __restrict__ H,
    const float* __restrict__ g, const float* __restrict__ bb, int M, int K) {
    __shared__ float ln[8][130];
    const int t = threadIdx.x;
    const int c = t & 127;
    const int grp = __builtin_amdgcn_readfirstlane(t >> 7);
    const int r0 = blockIdx.x * 8 + grp * 2;
    float acc0 = 0.f, acc1 = 0.f;
    #pragma unroll 4
    for (int k0 = 0; k0 < K; k0 += 4) {
        float w0 = W[(size_t)(k0 + 0) * 128 + c];
        float w1 = W[(size_t)(k0 + 1) * 128 + c];
        float w2 = W[(size_t)(k0 + 2) * 128 + c];
        float w3 = W[(size_t)(k0 + 3) * 128 + c];
        float4 a0 = *(const float4*)&A[(size_t)(r0 + 0) * K + k0];
        float4 a1 = *(const float4*)&A[(size_t)(r0 + 1) * K + k0];
        acc0 = fmaf(a0.x, w0, acc0); acc0 = fmaf(a0.y, w1, acc0);
        acc0 = fmaf(a0.z, w2, acc0); acc0 = fmaf(a0.w, w3, acc0);
        acc1 = fmaf(a1.x, w0, acc1); acc1 = fmaf(a1.y, w1, acc1);
        acc1 = fmaf(a1.z, w2, acc1); acc1 = fmaf(a1.w, w3, acc1);
    }
    float bv = bias[c];
    float v0 = acc0 + bv + R[(size_t)(r0 + 0) * 128 + c];
    float v1 = acc1 + bv + R[(size_t)(r0 + 1) * 128 + c];
    ln[grp * 2 + 0][c] = v0;
    ln[grp * 2 + 1][c] = v1;
    if (r0 + 0 < M) C[(size_t)(r0 + 0) * 128 + c] = v0;
    if (r0 + 1 < M) C[(size_t)(r0 + 1) * 128 + c] = v1;
    __syncthreads();
    const int wv = t >> 6, l = t & 63;
    float x0 = ln[wv][l], x1 = ln[wv][l + 64];
    float s = x0 + x1;
    for (int off = 32; off > 0; off >>= 1) s += __shfl_down(s, off);
    float mean = __shfl(s, 0) * (1.f / 128.f);
    float d0 = x0 - mean, d1 = x1 - mean;
    float vv = d0 * d0 + d1 * d1;
    for (int off = 32; off > 0; off >>= 1) vv += __shfl_down(vv, off);
    float var = __shfl(vv, 0) * (1.f / 128.f);
    float rstd = rsqrtf(var + 1e-5f);
    const int hrow = blockIdx.x * 8 + wv;
    H[(size_t)hrow * 128 + l]      = d0 * rstd * g[l] + bb[l];
    H[(size_t)hrow * 128 + 64 + l] = d1 * rstd * g[l + 64] + bb[l + 64];
}

// ---------------- attention v8: fp32, QB=4, Q-tile 32, 128-key tiles ------------
// grid (79, 8 heads), block 256 (4 waves) -> 632 blocks, ALL co-resident at
// 4 blocks/CU (LDS 20.7 KB, VGPR-limited). qg = t&7 -> 4 query rows;
// chunk = t>>3 (32 chunks x 4 keys per 128-key tile).
// Swizzle r*20 + ((r>>2)&7)*4: the hot-loop read set {rows 4c+kx, c=0..7}
// maps to banks {0,20,8,28,16,4,24,12} -> conflict-free (verified by hand).
__device__ __forceinline__ int kvswz(int r) { return r * 20 + ((r >> 2) & 7) * 4; }

__global__ __launch_bounds__(256, 4) void attn_kernel(
    const float* __restrict__ qkv, float* __restrict__ O) {
    __shared__ float lds[5184];            // Ks [0,2592), Vs [2592,5184)
    float* Ks = lds;
    float* Vs = lds + 2592;
    const int t = threadIdx.x;
    const int qg = t & 7;
    const int chunk = t >> 3;              // 0..31
    const int head = blockIdx.y;
    const int qbase = blockIdx.x * 32 + qg * 4;
    const float SC = 0.25f * 1.4426950408889634f;   // log2e / sqrt(dh)

    float4 q[4][4];
    #pragma unroll
    for (int i = 0; i < 4; ++i) {
        if (qbase + i < SEQ) {
            const float4* qp = (const float4*)&qkv[(size_t)(qbase + i) * 384 + head * 16];
            #pragma unroll
            for (int j = 0; j < 4; ++j) {
                float4 v = qp[j];
                v.x *= SC; v.y *= SC; v.z *= SC; v.w *= SC;
                q[i][j] = v;
            }
        } else {
            #pragma unroll
            for (int j = 0; j < 4; ++j) q[i][j] = make_float4(0.f, 0.f, 0.f, 0.f);
        }
    }
    float m[4] = {-INFINITY, -INFINITY, -INFINITY, -INFINITY};
    float l[4] = {0.f, 0.f, 0.f, 0.f};
    float4 acc[4][4];
    #pragma unroll
    for (int i = 0; i < 4; ++i)
        #pragma unroll
        for (int j = 0; j < 4; ++j) acc[i][j] = make_float4(0.f, 0.f, 0.f, 0.f);

    for (int tile0 = 0; tile0 < SEQ; tile0 += 128) {
        if (tile0) __syncthreads();
        // stage: waves 0-1 -> K rows, waves 2-3 -> V rows
        if (t < 128) {
            int j = tile0 + t;
            if (j < SEQ) {
                const float4* kp = (const float4*)&qkv[(size_t)j * 384 + 128 + head * 16];
                float4* kd = (float4*)&Ks[kvswz(t)];
                kd[0] = kp[0]; kd[1] = kp[1]; kd[2] = kp[2]; kd[3] = kp[3];
            }
        } else {
            int j = tile0 + t - 128;
            if (j < SEQ) {
                const float4* vp = (const float4*)&qkv[(size_t)j * 384 + 256 + head * 16];
                float4* vd = (float4*)&Vs[kvswz(t - 128)];
                vd[0] = vp[0]; vd[1] = vp[1]; vd[2] = vp[2]; vd[3] = vp[3];
            }
        }
        __syncthreads();
        int cnt = SEQ - tile0; if (cnt > 128) cnt = 128;
        const int base = chunk * 4;
        if (base < cnt) {   // cnt is a multiple of 4 -> full key groups always
            float s[4][4];   // [key][query]
            #pragma unroll
            for (int kx = 0; kx < 4; ++kx) {
                const float4* kr = (const float4*)&Ks[kvswz(base + kx)];
                float4 k0 = kr[0], k1 = kr[1], k2 = kr[2], k3 = kr[3];
                #pragma unroll
                for (int qi = 0; qi < 4; ++qi) {
                    float d = q[qi][0].x * k0.x + q[qi][0].y * k0.y + q[qi][0].z * k0.z + q[qi][0].w * k0.w;
                    d += q[qi][1].x * k1.x + q[qi][1].y * k1.y + q[qi][1].z * k1.z + q[qi][1].w * k1.w;
                    d += q[qi][2].x * k2.x + q[qi][2].y * k2.y + q[qi][2].z * k2.z + q[qi][2].w * k2.w;
                    d += q[qi][3].x * k3.x + q[qi][3].y * k3.y + q[qi][3].z * k3.z + q[qi][3].w * k3.w;
                    s[kx][qi] = d;
                }
            }
            float e[4][4];
            #pragma unroll
            for (int qi = 0; qi < 4; ++qi) {
                float gm = fmaxf(fmaxf(s[0][qi], s[1][qi]), fmaxf(s[2][qi], s[3][qi]));
                float nm = fmaxf(m[qi], gm);
                float corr = fexp2(m[qi] - nm);
                float e0 = fexp2(s[0][qi] - nm), e1 = fexp2(s[1][qi] - nm);
                float e2 = fexp2(s[2][qi] - nm), e3 = fexp2(s[3][qi] - nm);
                e[0][qi] = e0; e[1][qi] = e1; e[2][qi] = e2; e[3][qi] = e3;
                l[qi] = fmaf(l[qi], corr, (e0 + e1) + (e2 + e3));
                m[qi] = nm;
                #pragma unroll
                for (int j2 = 0; j2 < 4; ++j2) {
                    acc[qi][j2].x *= corr; acc[qi][j2].y *= corr;
                    acc[qi][j2].z *= corr; acc[qi][j2].w *= corr;
                }
            }
            #pragma unroll
            for (int kx = 0; kx < 4; ++kx) {
                const float4* vr = (const float4*)&Vs[kvswz(base + kx)];
                float4 v0 = vr[0], v1 = vr[1], v2 = vr[2], v3 = vr[3];
                #pragma unroll
                for (int qi = 0; qi < 4; ++qi) {
                    float ee = e[kx][qi];
                    acc[qi][0].x = fmaf(ee, v0.x, acc[qi][0].x);
                    acc[qi][0].y = fmaf(ee, v0.y, acc[qi][0].y);
                    acc[qi][0].z = fmaf(ee, v0.z, acc[qi][0].z);
                    acc[qi][0].w = fmaf(ee, v0.w, acc[qi][0].w);
                    acc[qi][1].x = fmaf(ee, v1.x, acc[qi][1].x);
                    acc[qi][1].y = fmaf(ee, v1.y, acc[qi][1].y);
                    acc[qi][1].z = fmaf(ee, v1.z, acc[qi][1].z);
                    acc[qi][1].w = fmaf(ee, v1.w, acc[qi][1].w);
                    acc[qi][2].x = fmaf(ee, v2.x, acc[qi][2].x);
                    acc[qi][2].y = fmaf(ee, v2.y, acc[qi][2].y);
                    acc[qi][2].z = fmaf(ee, v2.z, acc[qi][2].z);
                    acc[qi][2].w = fmaf(ee, v2.w, acc[qi][2].w);
                    acc[qi][3].x = fmaf(ee, v3.x, acc[qi][3].x);
                    acc[qi][3].y = fmaf(ee, v3.y, acc[qi][3].y);
                    acc[qi][3].z = fmaf(ee, v3.z, acc[qi][3].z);
                    acc[qi][3].w = fmaf(ee, v3.w, acc[qi][3].w);
                }
            }
        }
    }
    __syncthreads();

    // merge the 8 chunk-partials sharing qg within each wave (masks 8,16,32)
    #pragma unroll
    for (int mask = 8; mask <= 32; mask <<= 1) {
        #pragma unroll
        for (int qi = 0; qi < 4; ++qi) {
            float m2 = __shfl_xor(m[qi], mask);
            float l2 = __shfl_xor(l[qi], mask);
            float M = fmaxf(m[qi], m2);
            float c1 = fexp2(m[qi] - M), c2 = fexp2(m2 - M);
            l[qi] = l[qi] * c1 + l2 * c2;
            #pragma unroll
            for (int j2 = 0; j2 < 4; ++j2) {
                float4 o = acc[qi][j2];
                float4 o2;
                o2.x = __shfl_xor(o.x, mask);
                o2.y = __shfl_xor(o.y, mask);
                o2.z = __shfl_xor(o.z, mask);
                o2.w = __shfl_xor(o.w, mask);
                o.x = o.x * c1 + o2.x * c2;
                o.y = o.y * c1 + o2.y * c2;
                o.z = o.z * c1 + o2.z * c2;
                o.w = o.w * c1 + o2.w * c2;
                acc[qi][j2] = o;
            }
            m[qi] = M;
        }
    }
    // 4 wave-partials per (qg,qi): 4 waves * 8 qg * 4 qi = 128 slots
    float* pacc = lds;            // 128*16 = 2048
    float* pm   = lds + 2048;     // 128
    float* pl   = lds + 2176;     // 128
    const int wv = t >> 6;
    if ((t & 63) < 8) {
        #pragma unroll
        for (int qi = 0; qi < 4; ++qi) {
            int slot = (wv * 8 + qg) * 4 + qi;
            float4* dst = (float4*)&pacc[slot * 16];
            dst[0] = acc[qi][0]; dst[1] = acc[qi][1];
            dst[2] = acc[qi][2]; dst[3] = acc[qi][3];
            pm[slot] = m[qi]; pl[slot] = l[qi];
        }
    }
    __syncthreads();
    if (t < 128) {
        const int row = t >> 2;           // 0..31
        const int part = t & 3;
        const int qrow = blockIdx.x * 32 + row;
        if (qrow < SEQ) {
            const int qg2 = row >> 2, qi2 = row & 3;
            float M = -INFINITY;
            #pragma unroll
            for (int w = 0; w < 4; ++w)
                M = fmaxf(M, pm[(w * 8 + qg2) * 4 + qi2]);
            float L = 0.f;
            float4 o = make_float4(0.f, 0.f, 0.f, 0.f);
            #pragma unroll
            for (int w = 0; w < 4; ++w) {
                int slot = (w * 8 + qg2) * 4 + qi2;
                float wgt = fexp2(pm[slot] - M);
                L = fmaf(pl[slot], wgt, L);
                float4 pa = ((const float4*)&pacc[slot * 16])[part];
                o.x = fmaf(pa.x, wgt, o.x); o.y = fmaf(pa.y, wgt, o.y);
                o.z = fmaf(pa.z, wgt, o.z); o.w = fmaf(pa.w, wgt, o.w);
            }
            float inv = 1.f / L;
            o.x *= inv; o.y *= inv; o.z *= inv; o.w *= inv;
            ((float4*)&O[(size_t)qrow * 128 + head * 16])[part] = o;
        }
    }
}

// ---- region + map_fuse + channel-LN stats (fused) ------------------------------
__global__ __launch_bounds__(256) void region_fuse_stats_kernel(
    const float* __restrict__ sup, const float* __restrict__ qry,
    const float* __restrict__ X, float* __restrict__ fused,
    float* __restrict__ MEAN, float* __restrict__ RSTD) {
    __shared__ float key0[2048];   // 16 x 128
    __shared__ float rfac[100];
    const int b = blockIdx.x;
    const int t = threadIdx.x;
    const float* feat = (b < 25) ? (sup + (size_t)b * 12800) : (qry + (size_t)(b - 25) * 12800);
    for (int i = t; i < 2048; i += 256) key0[i] = X[i];
    __syncthreads();
    if (t < 100) {
        float dots[16];
        #pragma unroll
        for (int mm = 0; mm < 16; ++mm) dots[mm] = 0.f;
        float s = 0.f, ss = 0.f;
        for (int c = 0; c < 128; ++c) {
            float f = feat[c * 100 + t];
            s += f; ss += f * f;
            #pragma unroll
            for (int mm = 0; mm < 16; ++mm) dots[mm] += f * key0[mm * 128 + c];
        }
        float mean16 = 0.f;
        #pragma unroll
        for (int mm = 0; mm < 16; ++mm) mean16 += 1.f / (1.f + expf(-dots[mm] * (1.f / 128.f)));
        float r = mean16 * (1.f / 16.f) + 1.f;
        rfac[t] = r;
        float mr = s * (1.f / 128.f);
        float vr = ss * (1.f / 128.f) - mr * mr;
        MEAN[b * 128 + t] = mr * r;
        RSTD[b * 128 + t] = rsqrtf(vr * r * r + 1e-6f);
    }
    __syncthreads();
    for (int i = t; i < 12800; i += 256)
        fused[(size_t)b * 12800 + i] = feat[i] * rfac[i % 100];
}

// ---------------- 3x3 conv, pad 1, 10x10 images --------------------------------
template<int CIN, bool RELU, bool FUSE_LN>
__global__ __launch_bounds__(256) void conv3x3_kernel(
    const float* __restrict__ in, const float* __restrict__ w,
    const float* __restrict__ MEAN, const float* __restrict__ RSTD,
    const float* __restrict__ g, const float* __restrict__ bb,
    float* __restrict__ out) {
    __shared__ float sin_[32 * 144];
    const int b = blockIdx.x;
    const int base_to = blockIdx.y * 8;
    const int t = threadIdx.x;
    const int h = __builtin_amdgcn_readfirstlane(t >> 7);   // wave-uniform
    const int p = t & 127;
    const int py = p / 10, px = p - py * 10;
    const bool active = p < 100;
    float acc[4] = {0.f, 0.f, 0.f, 0.f};
    for (int cb = 0; cb < CIN; cb += 32) {
        if (cb) __syncthreads();
        for (int i = t; i < 32 * 144; i += 256) {
            int c = i / 144, pos = i - c * 144;
            int y = pos / 12 - 1, x = pos % 12 - 1;
            float v = 0.f;
            if ((unsigned)y < 10u && (unsigned)x < 10u) {
                int pp = y * 10 + x;
                float raw = in[(size_t)b * CIN * 100 + (cb + c) * 100 + pp];
                if (FUSE_LN)
                    v = (raw - MEAN[b * 128 + pp]) * RSTD[b * 128 + pp] * g[cb + c] + bb[cb + c];
                else
                    v = raw;
            }
            sin_[i] = v;
        }
        __syncthreads();
        if (active) {
            const float* wbase = w + ((size_t)(base_to + h * 4) * CIN + cb) * 9;
            for (int c = 0; c < 32; ++c) {
                const float* sp = &sin_[c * 144 + py * 12 + px];
                float pix[9];
                #pragma unroll
                for (int k = 0; k < 9; ++k) pix[k] = sp[(k / 3) * 12 + (k % 3)];
                #pragma unroll
                for (int j = 0; j < 4; ++j) {
                    const float* wq = wbase + ((size_t)j * CIN + c) * 9;
                    #pragma unroll
                    for (int k = 0; k < 9; ++k) acc[j] = fmaf(pix[k], wq[k], acc[j]);
                }
            }
        }
    }
    if (active) {
        #pragma unroll
        for (int j = 0; j < 4; ++j) {
            float v = acc[j];
            if (RELU) v = fmaxf(v, 0.f);
            out[(size_t)b * 3200 + (base_to + h * 4 + j) * 100 + p] = v;
        }
    }
}

// ---------------- final pooling -------------------------------------------------
__global__ __launch_bounds__(256) void rfm_out_kernel(
    const float* __restrict__ conv4, const float* __restrict__ fused, float* __restrict__ out) {
    __shared__ float sig[3200];
    __shared__ float sf[12800];
    const int b = blockIdx.x;
    const int t = threadIdx.x;
    for (int i = t; i < 3200; i += 256) sig[i] = 1.f / (1.f + expf(-conv4[(size_t)b * 3200 + i]));
    for (int i = t; i < 12800; i += 256) sf[i] = fused[(size_t)b * 12800 + i];
    __syncthreads();
    for (int o = t; o < 4096; o += 256) {
        int c = o >> 5, tt = o & 31;
        float acc = 0.f;
        for (int p = 0; p < 100; ++p) acc += sig[tt * 100 + p] * sf[c * 100 + p];
        out[(size_t)b * 4096 + o] = acc * 0.01f;
    }
}

extern "C" void kernel_launch(void* const* d_in, const int* in_sizes, int n_in,
                              void* d_out, int out_size, void* d_ws, size_t ws_size,
                              hipStream_t stream) {
    (void)in_sizes; (void)n_in; (void)out_size; (void)ws_size;
    const float* sup    = (const float*)d_in[0];
    const float* qry    = (const float*)d_in[1];
    const float* td     = (const float*)d_in[2];
    const float* ln1_g  = (const float*)d_in[3];
    const float* ln1_b  = (const float*)d_in[4];
    const float* qkv_w  = (const float*)d_in[5];
    const float* qkv_b  = (const float*)d_in[6];
    const float* out_w  = (const float*)d_in[7];
    const float* out_b  = (const float*)d_in[8];
    const float* ln2_g  = (const float*)d_in[9];
    const float* ln2_b  = (const float*)d_in[10];
    const float* mlp_w1 = (const float*)d_in[11];
    const float* mlp_b1 = (const float*)d_in[12];
    const float* mlp_w2 = (const float*)d_in[13];
    const float* mlp_b2 = (const float*)d_in[14];
    const float* rg     = (const float*)d_in[15];
    const float* rb     = (const float*)d_in[16];
    const float* c1     = (const float*)d_in[17];
    const float* c2     = (const float*)d_in[18];
    const float* c3     = (const float*)d_in[19];
    const float* c4     = (const float*)d_in[20];
    float* out = (float*)d_out;

    // buffers padded to 2520 rows for unguarded 8-row GEMM blocks
    float* ws   = (float*)d_ws;
    float* X    = ws;                  // 322560
    float* H    = X + 322560;          // 322560
    float* QKV  = H + 322560;          // 967680
    float* Obuf = QKV + 967680;        // 322560
    float* MLPH = Obuf + 322560;       // 1290240
    float* FUSED= MLPH + 1290240;      // 1280000
    float* MEAN = FUSED + 1280000;     // 12800
    float* RSTD = MEAN + 12800;        // 12800
    float* CB1  = RSTD + 12800;        // 320000
    float* CB2  = CB1 + 320000;        // 320000

    const int SG = (SEQ + 7) / 8;      // 315 blocks

    concat_ln_kernel<<<SEQ, 64, 0, stream>>>(td, sup, ln1_g, ln1_b, X, H);
    for (int i = 0; i < 2; ++i) {
        sgemm_kernel<384, 8, 0, false><<<SG, 384, 0, stream>>>(
            H, qkv_w + (size_t)i * 128 * 384, qkv_b + i * 384, nullptr, QKV, SEQ, 128);
        attn_kernel<<<dim3((SEQ + 31) / 32, 8), 256, 0, stream>>>(QKV, Obuf);
        sgemm_ln_kernel<<<SG, 512, 0, stream>>>(
            Obuf, out_w + (size_t)i * 128 * 128, out_b + i * 128, X, X, H,
            ln2_g + i * 128, ln2_b + i * 128, SEQ, 128);
        sgemm_kernel<512, 8, 1, false><<<SG, 512, 0, stream>>>(
            H, mlp_w1 + (size_t)i * 128 * 512, mlp_b1 + i * 512, nullptr, MLPH, SEQ, 128);
        const float* ng = (i == 0) ? ln1_g + 128 : ln1_g;
        const float* nb = (i == 0) ? ln1_b + 128 : ln1_b;
        sgemm_ln_kernel<<<SG, 512, 0, stream>>>(
            MLPH, mlp_w2 + (size_t)i * 512 * 128, mlp_b2 + i * 128, X, X, H,
            ng, nb, SEQ, 512);
    }
    region_fuse_stats_kernel<<<100, 256, 0, stream>>>(sup, qry, X, FUSED, MEAN, RSTD);
    conv3x3_kernel<128, true,  true ><<<dim3(100, 4), 256, 0, stream>>>(FUSED, c1, MEAN, RSTD, rg, rb, CB1);
    conv3x3_kernel< 32, true,  false><<<dim3(100, 4), 256, 0, stream>>>(CB1, c2, nullptr, nullptr, nullptr, nullptr, CB2);
    conv3x3_kernel< 32, true,  false><<<dim3(100, 4), 256, 0, stream>>>(CB2, c3, nullptr, nullptr, nullptr, nullptr, CB1);
    conv3x3_kernel< 32, false, false><<<dim3(100, 4), 256, 0, stream>>>(CB1, c4, nullptr, nullptr, nullptr, nullptr, CB2);
    rfm_out_kernel<<<100, 256, 0, stream>>>(CB2, FUSED, out);
}

// Round 9
// 596.614 us; speedup vs baseline: 2.1227x; 2.1227x over previous
//
#include <hip/hip_runtime.h>
#include <math.h>

#define SEQ 2516
#define CDIM 128

__device__ __forceinline__ float gelu_exact(float x) {
    return x * 0.5f * (1.0f + erff(x * 0.7071067811865475f));
}
__device__ __forceinline__ float fexp2(float x) { return __builtin_amdgcn_exp2f(x); }

// ---------------- concat + LN1(layer0): one wave per row ------------------------
__global__ __launch_bounds__(64) void concat_ln_kernel(
    const float* __restrict__ td, const float* __restrict__ sup,
    const float* __restrict__ g, const float* __restrict__ b,
    float* __restrict__ X, float* __restrict__ H) {
    const int row = blockIdx.x;
    const int t = threadIdx.x;
    float x0, x1;
    if (row < 16) {
        x0 = td[row * 128 + t];
        x1 = td[row * 128 + 64 + t];
    } else {
        int r = row - 16;
        int n = r / 100, p = r - n * 100;
        x0 = sup[n * 12800 + t * 100 + p];
        x1 = sup[n * 12800 + (t + 64) * 100 + p];
    }
    X[row * 128 + t] = x0;
    X[row * 128 + 64 + t] = x1;
    float s = x0 + x1;
    for (int off = 32; off > 0; off >>= 1) s += __shfl_down(s, off);
    float mean = __shfl(s, 0) * (1.f / 128.f);
    float d0 = x0 - mean, d1 = x1 - mean;
    float v = d0 * d0 + d1 * d1;
    for (int off = 32; off > 0; off >>= 1) v += __shfl_down(v, off);
    float var = __shfl(v, 0) * (1.f / 128.f);
    float rstd = rsqrtf(var + 1e-5f);
    H[row * 128 + t]      = d0 * rstd * g[t] + b[t];
    H[row * 128 + 64 + t] = d1 * rstd * g[t + 64] + b[t + 64];
}

// ---------------- skinny GEMM: 8 M-rows x N cols per block ----------------------
template<int N, int RPT, int ACT, bool RES>
__global__ __launch_bounds__(N * 8 / RPT) void sgemm_kernel(
    const float* __restrict__ A, const float* __restrict__ W,
    const float* __restrict__ bias, const float* __restrict__ R,
    float* __restrict__ C, int M, int K) {
    const int t = threadIdx.x;
    const int c = t % N;
    const int grp = __builtin_amdgcn_readfirstlane(t / N);
    const int r0 = blockIdx.x * 8 + grp * RPT;
    float acc[RPT];
    #pragma unroll
    for (int i = 0; i < RPT; ++i) acc[i] = 0.f;
    #pragma unroll 4
    for (int k0 = 0; k0 < K; k0 += 4) {
        float w0 = W[(size_t)(k0 + 0) * N + c];
        float w1 = W[(size_t)(k0 + 1) * N + c];
        float w2 = W[(size_t)(k0 + 2) * N + c];
        float w3 = W[(size_t)(k0 + 3) * N + c];
        #pragma unroll
        for (int i = 0; i < RPT; ++i) {
            float4 a4 = *(const float4*)&A[(size_t)(r0 + i) * K + k0];
            acc[i] = fmaf(a4.x, w0, acc[i]);
            acc[i] = fmaf(a4.y, w1, acc[i]);
            acc[i] = fmaf(a4.z, w2, acc[i]);
            acc[i] = fmaf(a4.w, w3, acc[i]);
        }
    }
    float bv = bias[c];
    #pragma unroll
    for (int i = 0; i < RPT; ++i) {
        int row = r0 + i;
        if (row < M) {
            float v = acc[i] + bv;
            if (ACT == 1) v = gelu_exact(v);
            if (RES) v += R[(size_t)row * N + c];
            C[(size_t)row * N + c] = v;
        }
    }
}

// ------- skinny GEMM N=128 + residual + row-LN epilogue (writes C and H) --------
__global__ __launch_bounds__(512) void sgemm_ln_kernel(
    const float* __restrict__ A, const float* __restrict__ W,
    const float* __restrict__ bias, const float* __restrict__ R,
    float* __restrict__ C, float* __restrict__ H,
    const float* __restrict__ g, const float* __restrict__ bb, int M, int K) {
    __shared__ float ln[8][130];
    const int t = threadIdx.x;
    const int c = t & 127;
    const int grp = __builtin_amdgcn_readfirstlane(t >> 7);
    const int r0 = blockIdx.x * 8 + grp * 2;
    float acc0 = 0.f, acc1 = 0.f;
    #pragma unroll 4
    for (int k0 = 0; k0 < K; k0 += 4) {
        float w0 = W[(size_t)(k0 + 0) * 128 + c];
        float w1 = W[(size_t)(k0 + 1) * 128 + c];
        float w2 = W[(size_t)(k0 + 2) * 128 + c];
        float w3 = W[(size_t)(k0 + 3) * 128 + c];
        float4 a0 = *(const float4*)&A[(size_t)(r0 + 0) * K + k0];
        float4 a1 = *(const float4*)&A[(size_t)(r0 + 1) * K + k0];
        acc0 = fmaf(a0.x, w0, acc0); acc0 = fmaf(a0.y, w1, acc0);
        acc0 = fmaf(a0.z, w2, acc0); acc0 = fmaf(a0.w, w3, acc0);
        acc1 = fmaf(a1.x, w0, acc1); acc1 = fmaf(a1.y, w1, acc1);
        acc1 = fmaf(a1.z, w2, acc1); acc1 = fmaf(a1.w, w3, acc1);
    }
    float bv = bias[c];
    float v0 = acc0 + bv + R[(size_t)(r0 + 0) * 128 + c];
    float v1 = acc1 + bv + R[(size_t)(r0 + 1) * 128 + c];
    ln[grp * 2 + 0][c] = v0;
    ln[grp * 2 + 1][c] = v1;
    if (r0 + 0 < M) C[(size_t)(r0 + 0) * 128 + c] = v0;
    if (r0 + 1 < M) C[(size_t)(r0 + 1) * 128 + c] = v1;
    __syncthreads();
    const int wv = t >> 6, l = t & 63;
    float x0 = ln[wv][l], x1 = ln[wv][l + 64];
    float s = x0 + x1;
    for (int off = 32; off > 0; off >>= 1) s += __shfl_down(s, off);
    float mean = __shfl(s, 0) * (1.f / 128.f);
    float d0 = x0 - mean, d1 = x1 - mean;
    float vv = d0 * d0 + d1 * d1;
    for (int off = 32; off > 0; off >>= 1) vv += __shfl_down(vv, off);
    float var = __shfl(vv, 0) * (1.f / 128.f);
    float rstd = rsqrtf(var + 1e-5f);
    const int hrow = blockIdx.x * 8 + wv;
    H[(size_t)hrow * 128 + l]      = d0 * rstd * g[l] + bb[l];
    H[(size_t)hrow * 128 + 64 + l] = d1 * rstd * g[l + 64] + bb[l + 64];
}

// ---------------- attention v9: fp32, QB=4, Q-tile 32, 128-key tiles ------------
// grid (79, 8 heads), block 256 (4 waves). qg = t&7 -> 4 query rows;
// chunk = t>>3 (32 chunks x 4 keys per 128-key tile).
// Swizzle r*20 + ((r>>2)&7)*4: hot-loop read set {rows 4c+kx, c=0..7} maps to
// banks {0,20,8,28,16,4,24,12} -> conflict-free; staging writes <=2-way.
// NO min-waves launch bound: R8's (256,4) forced the allocator to 64 VGPRs and
// spilled the q/acc working set to scratch (1.4 GB HBM traffic/dispatch).
__device__ __forceinline__ int kvswz(int r) { return r * 20 + ((r >> 2) & 7) * 4; }

__global__ __launch_bounds__(256) void attn_kernel(
    const float* __restrict__ qkv, float* __restrict__ O) {
    __shared__ float lds[5184];            // Ks [0,2592), Vs [2592,5184)
    float* Ks = lds;
    float* Vs = lds + 2592;
    const int t = threadIdx.x;
    const int qg = t & 7;
    const int chunk = t >> 3;              // 0..31
    const int head = blockIdx.y;
    const int qbase = blockIdx.x * 32 + qg * 4;
    const float SC = 0.25f * 1.4426950408889634f;   // log2e / sqrt(dh)

    float4 q[4][4];
    #pragma unroll
    for (int i = 0; i < 4; ++i) {
        if (qbase + i < SEQ) {
            const float4* qp = (const float4*)&qkv[(size_t)(qbase + i) * 384 + head * 16];
            #pragma unroll
            for (int j = 0; j < 4; ++j) {
                float4 v = qp[j];
                v.x *= SC; v.y *= SC; v.z *= SC; v.w *= SC;
                q[i][j] = v;
            }
        } else {
            #pragma unroll
            for (int j = 0; j < 4; ++j) q[i][j] = make_float4(0.f, 0.f, 0.f, 0.f);
        }
    }
    float m[4] = {-INFINITY, -INFINITY, -INFINITY, -INFINITY};
    float l[4] = {0.f, 0.f, 0.f, 0.f};
    float4 acc[4][4];
    #pragma unroll
    for (int i = 0; i < 4; ++i)
        #pragma unroll
        for (int j = 0; j < 4; ++j) acc[i][j] = make_float4(0.f, 0.f, 0.f, 0.f);

    for (int tile0 = 0; tile0 < SEQ; tile0 += 128) {
        if (tile0) __syncthreads();
        // stage: waves 0-1 -> K rows, waves 2-3 -> V rows
        if (t < 128) {
            int j = tile0 + t;
            if (j < SEQ) {
                const float4* kp = (const float4*)&qkv[(size_t)j * 384 + 128 + head * 16];
                float4* kd = (float4*)&Ks[kvswz(t)];
                kd[0] = kp[0]; kd[1] = kp[1]; kd[2] = kp[2]; kd[3] = kp[3];
            }
        } else {
            int j = tile0 + t - 128;
            if (j < SEQ) {
                const float4* vp = (const float4*)&qkv[(size_t)j * 384 + 256 + head * 16];
                float4* vd = (float4*)&Vs[kvswz(t - 128)];
                vd[0] = vp[0]; vd[1] = vp[1]; vd[2] = vp[2]; vd[3] = vp[3];
            }
        }
        __syncthreads();
        int cnt = SEQ - tile0; if (cnt > 128) cnt = 128;
        const int base = chunk * 4;
        if (base < cnt) {   // cnt is a multiple of 4 -> full key groups always
            float s[4][4];   // [key][query]
            #pragma unroll
            for (int kx = 0; kx < 4; ++kx) {
                const float4* kr = (const float4*)&Ks[kvswz(base + kx)];
                float4 k0 = kr[0], k1 = kr[1], k2 = kr[2], k3 = kr[3];
                #pragma unroll
                for (int qi = 0; qi < 4; ++qi) {
                    float d = q[qi][0].x * k0.x + q[qi][0].y * k0.y + q[qi][0].z * k0.z + q[qi][0].w * k0.w;
                    d += q[qi][1].x * k1.x + q[qi][1].y * k1.y + q[qi][1].z * k1.z + q[qi][1].w * k1.w;
                    d += q[qi][2].x * k2.x + q[qi][2].y * k2.y + q[qi][2].z * k2.z + q[qi][2].w * k2.w;
                    d += q[qi][3].x * k3.x + q[qi][3].y * k3.y + q[qi][3].z * k3.z + q[qi][3].w * k3.w;
                    s[kx][qi] = d;
                }
            }
            float e[4][4];
            #pragma unroll
            for (int qi = 0; qi < 4; ++qi) {
                float gm = fmaxf(fmaxf(s[0][qi], s[1][qi]), fmaxf(s[2][qi], s[3][qi]));
                float nm = fmaxf(m[qi], gm);
                float corr = fexp2(m[qi] - nm);
                float e0 = fexp2(s[0][qi] - nm), e1 = fexp2(s[1][qi] - nm);
                float e2 = fexp2(s[2][qi] - nm), e3 = fexp2(s[3][qi] - nm);
                e[0][qi] = e0; e[1][qi] = e1; e[2][qi] = e2; e[3][qi] = e3;
                l[qi] = fmaf(l[qi], corr, (e0 + e1) + (e2 + e3));
                m[qi] = nm;
                #pragma unroll
                for (int j2 = 0; j2 < 4; ++j2) {
                    acc[qi][j2].x *= corr; acc[qi][j2].y *= corr;
                    acc[qi][j2].z *= corr; acc[qi][j2].w *= corr;
                }
            }
            #pragma unroll
            for (int kx = 0; kx < 4; ++kx) {
                const float4* vr = (const float4*)&Vs[kvswz(base + kx)];
                float4 v0 = vr[0], v1 = vr[1], v2 = vr[2], v3 = vr[3];
                #pragma unroll
                for (int qi = 0; qi < 4; ++qi) {
                    float ee = e[kx][qi];
                    acc[qi][0].x = fmaf(ee, v0.x, acc[qi][0].x);
                    acc[qi][0].y = fmaf(ee, v0.y, acc[qi][0].y);
                    acc[qi][0].z = fmaf(ee, v0.z, acc[qi][0].z);
                    acc[qi][0].w = fmaf(ee, v0.w, acc[qi][0].w);
                    acc[qi][1].x = fmaf(ee, v1.x, acc[qi][1].x);
                    acc[qi][1].y = fmaf(ee, v1.y, acc[qi][1].y);
                    acc[qi][1].z = fmaf(ee, v1.z, acc[qi][1].z);
                    acc[qi][1].w = fmaf(ee, v1.w, acc[qi][1].w);
                    acc[qi][2].x = fmaf(ee, v2.x, acc[qi][2].x);
                    acc[qi][2].y = fmaf(ee, v2.y, acc[qi][2].y);
                    acc[qi][2].z = fmaf(ee, v2.z, acc[qi][2].z);
                    acc[qi][2].w = fmaf(ee, v2.w, acc[qi][2].w);
                    acc[qi][3].x = fmaf(ee, v3.x, acc[qi][3].x);
                    acc[qi][3].y = fmaf(ee, v3.y, acc[qi][3].y);
                    acc[qi][3].z = fmaf(ee, v3.z, acc[qi][3].z);
                    acc[qi][3].w = fmaf(ee, v3.w, acc[qi][3].w);
                }
            }
        }
    }
    __syncthreads();

    // merge the 8 chunk-partials sharing qg within each wave (masks 8,16,32)
    #pragma unroll
    for (int mask = 8; mask <= 32; mask <<= 1) {
        #pragma unroll
        for (int qi = 0; qi < 4; ++qi) {
            float m2 = __shfl_xor(m[qi], mask);
            float l2 = __shfl_xor(l[qi], mask);
            float M = fmaxf(m[qi], m2);
            float c1 = fexp2(m[qi] - M), c2 = fexp2(m2 - M);
            l[qi] = l[qi] * c1 + l2 * c2;
            #pragma unroll
            for (int j2 = 0; j2 < 4; ++j2) {
                float4 o = acc[qi][j2];
                float4 o2;
                o2.x = __shfl_xor(o.x, mask);
                o2.y = __shfl_xor(o.y, mask);
                o2.z = __shfl_xor(o.z, mask);
                o2.w = __shfl_xor(o.w, mask);
                o.x = o.x * c1 + o2.x * c2;
                o.y = o.y * c1 + o2.y * c2;
                o.z = o.z * c1 + o2.z * c2;
                o.w = o.w * c1 + o2.w * c2;
                acc[qi][j2] = o;
            }
            m[qi] = M;
        }
    }
    // 4 wave-partials per (qg,qi): 4 waves * 8 qg * 4 qi = 128 slots
    float* pacc = lds;            // 128*16 = 2048
    float* pm   = lds + 2048;     // 128
    float* pl   = lds + 2176;     // 128
    const int wv = t >> 6;
    if ((t & 63) < 8) {
        #pragma unroll
        for (int qi = 0; qi < 4; ++qi) {
            int slot = (wv * 8 + qg) * 4 + qi;
            float4* dst = (float4*)&pacc[slot * 16];
            dst[0] = acc[qi][0]; dst[1] = acc[qi][1];
            dst[2] = acc[qi][2]; dst[3] = acc[qi][3];
            pm[slot] = m[qi]; pl[slot] = l[qi];
        }
    }
    __syncthreads();
    if (t < 128) {
        const int row = t >> 2;           // 0..31
        const int part = t & 3;
        const int qrow = blockIdx.x * 32 + row;
        if (qrow < SEQ) {
            const int qg2 = row >> 2, qi2 = row & 3;
            float M = -INFINITY;
            #pragma unroll
            for (int w = 0; w < 4; ++w)
                M = fmaxf(M, pm[(w * 8 + qg2) * 4 + qi2]);
            float L = 0.f;
            float4 o = make_float4(0.f, 0.f, 0.f, 0.f);
            #pragma unroll
            for (int w = 0; w < 4; ++w) {
                int slot = (w * 8 + qg2) * 4 + qi2;
                float wgt = fexp2(pm[slot] - M);
                L = fmaf(pl[slot], wgt, L);
                float4 pa = ((const float4*)&pacc[slot * 16])[part];
                o.x = fmaf(pa.x, wgt, o.x); o.y = fmaf(pa.y, wgt, o.y);
                o.z = fmaf(pa.z, wgt, o.z); o.w = fmaf(pa.w, wgt, o.w);
            }
            float inv = 1.f / L;
            o.x *= inv; o.y *= inv; o.z *= inv; o.w *= inv;
            ((float4*)&O[(size_t)qrow * 128 + head * 16])[part] = o;
        }
    }
}

// ---- region + map_fuse + channel-LN stats (fused) ------------------------------
__global__ __launch_bounds__(256) void region_fuse_stats_kernel(
    const float* __restrict__ sup, const float* __restrict__ qry,
    const float* __restrict__ X, float* __restrict__ fused,
    float* __restrict__ MEAN, float* __restrict__ RSTD) {
    __shared__ float key0[2048];   // 16 x 128
    __shared__ float rfac[100];
    const int b = blockIdx.x;
    const int t = threadIdx.x;
    const float* feat = (b < 25) ? (sup + (size_t)b * 12800) : (qry + (size_t)(b - 25) * 12800);
    for (int i = t; i < 2048; i += 256) key0[i] = X[i];
    __syncthreads();
    if (t < 100) {
        float dots[16];
        #pragma unroll
        for (int mm = 0; mm < 16; ++mm) dots[mm] = 0.f;
        float s = 0.f, ss = 0.f;
        for (int c = 0; c < 128; ++c) {
            float f = feat[c * 100 + t];
            s += f; ss += f * f;
            #pragma unroll
            for (int mm = 0; mm < 16; ++mm) dots[mm] += f * key0[mm * 128 + c];
        }
        float mean16 = 0.f;
        #pragma unroll
        for (int mm = 0; mm < 16; ++mm) mean16 += 1.f / (1.f + expf(-dots[mm] * (1.f / 128.f)));
        float r = mean16 * (1.f / 16.f) + 1.f;
        rfac[t] = r;
        float mr = s * (1.f / 128.f);
        float vr = ss * (1.f / 128.f) - mr * mr;
        MEAN[b * 128 + t] = mr * r;
        RSTD[b * 128 + t] = rsqrtf(vr * r * r + 1e-6f);
    }
    __syncthreads();
    for (int i = t; i < 12800; i += 256)
        fused[(size_t)b * 12800 + i] = feat[i] * rfac[i % 100];
}

// ---------------- 3x3 conv, pad 1, 10x10 images --------------------------------
template<int CIN, bool RELU, bool FUSE_LN>
__global__ __launch_bounds__(256) void conv3x3_kernel(
    const float* __restrict__ in, const float* __restrict__ w,
    const float* __restrict__ MEAN, const float* __restrict__ RSTD,
    const float* __restrict__ g, const float* __restrict__ bb,
    float* __restrict__ out) {
    __shared__ float sin_[32 * 144];
    const int b = blockIdx.x;
    const int base_to = blockIdx.y * 8;
    const int t = threadIdx.x;
    const int h = __builtin_amdgcn_readfirstlane(t >> 7);   // wave-uniform
    const int p = t & 127;
    const int py = p / 10, px = p - py * 10;
    const bool active = p < 100;
    float acc[4] = {0.f, 0.f, 0.f, 0.f};
    for (int cb = 0; cb < CIN; cb += 32) {
        if (cb) __syncthreads();
        for (int i = t; i < 32 * 144; i += 256) {
            int c = i / 144, pos = i - c * 144;
            int y = pos / 12 - 1, x = pos % 12 - 1;
            float v = 0.f;
            if ((unsigned)y < 10u && (unsigned)x < 10u) {
                int pp = y * 10 + x;
                float raw = in[(size_t)b * CIN * 100 + (cb + c) * 100 + pp];
                if (FUSE_LN)
                    v = (raw - MEAN[b * 128 + pp]) * RSTD[b * 128 + pp] * g[cb + c] + bb[cb + c];
                else
                    v = raw;
            }
            sin_[i] = v;
        }
        __syncthreads();
        if (active) {
            const float* wbase = w + ((size_t)(base_to + h * 4) * CIN + cb) * 9;
            for (int c = 0; c < 32; ++c) {
                const float* sp = &sin_[c * 144 + py * 12 + px];
                float pix[9];
                #pragma unroll
                for (int k = 0; k < 9; ++k) pix[k] = sp[(k / 3) * 12 + (k % 3)];
                #pragma unroll
                for (int j = 0; j < 4; ++j) {
                    const float* wq = wbase + ((size_t)j * CIN + c) * 9;
                    #pragma unroll
                    for (int k = 0; k < 9; ++k) acc[j] = fmaf(pix[k], wq[k], acc[j]);
                }
            }
        }
    }
    if (active) {
        #pragma unroll
        for (int j = 0; j < 4; ++j) {
            float v = acc[j];
            if (RELU) v = fmaxf(v, 0.f);
            out[(size_t)b * 3200 + (base_to + h * 4 + j) * 100 + p] = v;
        }
    }
}

// ---------------- final pooling -------------------------------------------------
__global__ __launch_bounds__(256) void rfm_out_kernel(
    const float* __restrict__ conv4, const float* __restrict__ fused, float* __restrict__ out) {
    __shared__ float sig[3200];
    __shared__ float sf[12800];
    const int b = blockIdx.x;
    const int t = threadIdx.x;
    for (int i = t; i < 3200; i += 256) sig[i] = 1.f / (1.f + expf(-conv4[(size_t)b * 3200 + i]));
    for (int i = t; i < 12800; i += 256) sf[i] = fused[(size_t)b * 12800 + i];
    __syncthreads();
    for (int o = t; o < 4096; o += 256) {
        int c = o >> 5, tt = o & 31;
        float acc = 0.f;
        for (int p = 0; p < 100; ++p) acc += sig[tt * 100 + p] * sf[c * 100 + p];
        out[(size_t)b * 4096 + o] = acc * 0.01f;
    }
}

extern "C" void kernel_launch(void* const* d_in, const int* in_sizes, int n_in,
                              void* d_out, int out_size, void* d_ws, size_t ws_size,
                              hipStream_t stream) {
    (void)in_sizes; (void)n_in; (void)out_size; (void)ws_size;
    const float* sup    = (const float*)d_in[0];
    const float* qry    = (const float*)d_in[1];
    const float* td     = (const float*)d_in[2];
    const float* ln1_g  = (const float*)d_in[3];
    const float* ln1_b  = (const float*)d_in[4];
    const float* qkv_w  = (const float*)d_in[5];
    const float* qkv_b  = (const float*)d_in[6];
    const float* out_w  = (const float*)d_in[7];
    const float* out_b  = (const float*)d_in[8];
    const float* ln2_g  = (const float*)d_in[9];
    const float* ln2_b  = (const float*)d_in[10];
    const float* mlp_w1 = (const float*)d_in[11];
    const float* mlp_b1 = (const float*)d_in[12];
    const float* mlp_w2 = (const float*)d_in[13];
    const float* mlp_b2 = (const float*)d_in[14];
    const float* rg     = (const float*)d_in[15];
    const float* rb     = (const float*)d_in[16];
    const float* c1     = (const float*)d_in[17];
    const float* c2     = (const float*)d_in[18];
    const float* c3     = (const float*)d_in[19];
    const float* c4     = (const float*)d_in[20];
    float* out = (float*)d_out;

    // buffers padded to 2520 rows for unguarded 8-row GEMM blocks
    float* ws   = (float*)d_ws;
    float* X    = ws;                  // 322560
    float* H    = X + 322560;          // 322560
    float* QKV  = H + 322560;          // 967680
    float* Obuf = QKV + 967680;        // 322560
    float* MLPH = Obuf + 322560;       // 1290240
    float* FUSED= MLPH + 1290240;      // 1280000
    float* MEAN = FUSED + 1280000;     // 12800
    float* RSTD = MEAN + 12800;        // 12800
    float* CB1  = RSTD + 12800;        // 320000
    float* CB2  = CB1 + 320000;        // 320000

    const int SG = (SEQ + 7) / 8;      // 315 blocks

    concat_ln_kernel<<<SEQ, 64, 0, stream>>>(td, sup, ln1_g, ln1_b, X, H);
    for (int i = 0; i < 2; ++i) {
        sgemm_kernel<384, 8, 0, false><<<SG, 384, 0, stream>>>(
            H, qkv_w + (size_t)i * 128 * 384, qkv_b + i * 384, nullptr, QKV, SEQ, 128);
        attn_kernel<<<dim3((SEQ + 31) / 32, 8), 256, 0, stream>>>(QKV, Obuf);
        sgemm_ln_kernel<<<SG, 512, 0, stream>>>(
            Obuf, out_w + (size_t)i * 128 * 128, out_b + i * 128, X, X, H,
            ln2_g + i * 128, ln2_b + i * 128, SEQ, 128);
        sgemm_kernel<512, 8, 1, false><<<SG, 512, 0, stream>>>(
            H, mlp_w1 + (size_t)i * 128 * 512, mlp_b1 + i * 512, nullptr, MLPH, SEQ, 128);
        const float* ng = (i == 0) ? ln1_g + 128 : ln1_g;
        const float* nb = (i == 0) ? ln1_b + 128 : ln1_b;
        sgemm_ln_kernel<<<SG, 512, 0, stream>>>(
            MLPH, mlp_w2 + (size_t)i * 512 * 128, mlp_b2 + i * 128, X, X, H,
            ng, nb, SEQ, 512);
    }
    region_fuse_stats_kernel<<<100, 256, 0, stream>>>(sup, qry, X, FUSED, MEAN, RSTD);
    conv3x3_kernel<128, true,  true ><<<dim3(100, 4), 256, 0, stream>>>(FUSED, c1, MEAN, RSTD, rg, rb, CB1);
    conv3x3_kernel< 32, true,  false><<<dim3(100, 4), 256, 0, stream>>>(CB1, c2, nullptr, nullptr, nullptr, nullptr, CB2);
    conv3x3_kernel< 32, true,  false><<<dim3(100, 4), 256, 0, stream>>>(CB2, c3, nullptr, nullptr, nullptr, nullptr, CB1);
    conv3x3_kernel< 32, false, false><<<dim3(100, 4), 256, 0, stream>>>(CB1, c4, nullptr, nullptr, nullptr, nullptr, CB2);
    rfm_out_kernel<<<100, 256, 0, stream>>>(CB2, FUSED, out);
}

// Round 10
// 582.509 us; speedup vs baseline: 2.1741x; 1.0242x over previous
//
#include <hip/hip_runtime.h>
#include <math.h>

#define SEQ 2516
#define SEQP 2520
#define CDIM 128

__device__ __forceinline__ float gelu_exact(float x) {
    return x * 0.5f * (1.0f + erff(x * 0.7071067811865475f));
}
__device__ __forceinline__ float fexp2(float x) { return __builtin_amdgcn_exp2f(x); }

// ---------------- concat + LN1(layer0): one wave per row ------------------------
__global__ __launch_bounds__(64) void concat_ln_kernel(
    const float* __restrict__ td, const float* __restrict__ sup,
    const float* __restrict__ g, const float* __restrict__ b,
    float* __restrict__ X, float* __restrict__ H) {
    const int row = blockIdx.x;
    const int t = threadIdx.x;
    float x0, x1;
    if (row < 16) {
        x0 = td[row * 128 + t];
        x1 = td[row * 128 + 64 + t];
    } else {
        int r = row - 16;
        int n = r / 100, p = r - n * 100;
        x0 = sup[n * 12800 + t * 100 + p];
        x1 = sup[n * 12800 + (t + 64) * 100 + p];
    }
    X[row * 128 + t] = x0;
    X[row * 128 + 64 + t] = x1;
    float s = x0 + x1;
    for (int off = 32; off > 0; off >>= 1) s += __shfl_down(s, off);
    float mean = __shfl(s, 0) * (1.f / 128.f);
    float d0 = x0 - mean, d1 = x1 - mean;
    float v = d0 * d0 + d1 * d1;
    for (int off = 32; off > 0; off >>= 1) v += __shfl_down(v, off);
    float var = __shfl(v, 0) * (1.f / 128.f);
    float rstd = rsqrtf(var + 1e-5f);
    H[row * 128 + t]      = d0 * rstd * g[t] + b[t];
    H[row * 128 + 64 + t] = d1 * rstd * g[t + 64] + b[t + 64];
}

// ---------------- skinny GEMM: 8 M-rows x N cols per block ----------------------
template<int N, int RPT, int ACT, bool RES>
__global__ __launch_bounds__(N * 8 / RPT) void sgemm_kernel(
    const float* __restrict__ A, const float* __restrict__ W,
    const float* __restrict__ bias, const float* __restrict__ R,
    float* __restrict__ C, int M, int K) {
    const int t = threadIdx.x;
    const int c = t % N;
    const int grp = __builtin_amdgcn_readfirstlane(t / N);
    const int r0 = blockIdx.x * 8 + grp * RPT;
    float acc[RPT];
    #pragma unroll
    for (int i = 0; i < RPT; ++i) acc[i] = 0.f;
    #pragma unroll 4
    for (int k0 = 0; k0 < K; k0 += 4) {
        float w0 = W[(size_t)(k0 + 0) * N + c];
        float w1 = W[(size_t)(k0 + 1) * N + c];
        float w2 = W[(size_t)(k0 + 2) * N + c];
        float w3 = W[(size_t)(k0 + 3) * N + c];
        #pragma unroll
        for (int i = 0; i < RPT; ++i) {
            float4 a4 = *(const float4*)&A[(size_t)(r0 + i) * K + k0];
            acc[i] = fmaf(a4.x, w0, acc[i]);
            acc[i] = fmaf(a4.y, w1, acc[i]);
            acc[i] = fmaf(a4.z, w2, acc[i]);
            acc[i] = fmaf(a4.w, w3, acc[i]);
        }
    }
    float bv = bias[c];
    #pragma unroll
    for (int i = 0; i < RPT; ++i) {
        int row = r0 + i;
        if (row < M) {
            float v = acc[i] + bv;
            if (ACT == 1) v = gelu_exact(v);
            if (RES) v += R[(size_t)row * N + c];
            C[(size_t)row * N + c] = v;
        }
    }
}

// ------- skinny GEMM N=128 + residual + row-LN epilogue (writes C and H) --------
__global__ __launch_bounds__(512) void sgemm_ln_kernel(
    const float* __restrict__ A, const float* __restrict__ W,
    const float* __restrict__ bias, const float* __restrict__ R,
    float* __restrict__ C, float* __restrict__ H,
    const float* __restrict__ g, const float* __restrict__ bb, int M, int K) {
    __shared__ float ln[8][130];
    const int t = threadIdx.x;
    const int c = t & 127;
    const int grp = __builtin_amdgcn_readfirstlane(t >> 7);
    const int r0 = blockIdx.x * 8 + grp * 2;
    float acc0 = 0.f, acc1 = 0.f;
    #pragma unroll 4
    for (int k0 = 0; k0 < K; k0 += 4) {
        float w0 = W[(size_t)(k0 + 0) * 128 + c];
        float w1 = W[(size_t)(k0 + 1) * 128 + c];
        float w2 = W[(size_t)(k0 + 2) * 128 + c];
        float w3 = W[(size_t)(k0 + 3) * 128 + c];
        float4 a0 = *(const float4*)&A[(size_t)(r0 + 0) * K + k0];
        float4 a1 = *(const float4*)&A[(size_t)(r0 + 1) * K + k0];
        acc0 = fmaf(a0.x, w0, acc0); acc0 = fmaf(a0.y, w1, acc0);
        acc0 = fmaf(a0.z, w2, acc0); acc0 = fmaf(a0.w, w3, acc0);
        acc1 = fmaf(a1.x, w0, acc1); acc1 = fmaf(a1.y, w1, acc1);
        acc1 = fmaf(a1.z, w2, acc1); acc1 = fmaf(a1.w, w3, acc1);
    }
    float bv = bias[c];
    float v0 = acc0 + bv + R[(size_t)(r0 + 0) * 128 + c];
    float v1 = acc1 + bv + R[(size_t)(r0 + 1) * 128 + c];
    ln[grp * 2 + 0][c] = v0;
    ln[grp * 2 + 1][c] = v1;
    if (r0 + 0 < M) C[(size_t)(r0 + 0) * 128 + c] = v0;
    if (r0 + 1 < M) C[(size_t)(r0 + 1) * 128 + c] = v1;
    __syncthreads();
    const int wv = t >> 6, l = t & 63;
    float x0 = ln[wv][l], x1 = ln[wv][l + 64];
    float s = x0 + x1;
    for (int off = 32; off > 0; off >>= 1) s += __shfl_down(s, off);
    float mean = __shfl(s, 0) * (1.f / 128.f);
    float d0 = x0 - mean, d1 = x1 - mean;
    float vv = d0 * d0 + d1 * d1;
    for (int off = 32; off > 0; off >>= 1) vv += __shfl_down(vv, off);
    float var = __shfl(vv, 0) * (1.f / 128.f);
    float rstd = rsqrtf(var + 1e-5f);
    const int hrow = blockIdx.x * 8 + wv;
    H[(size_t)hrow * 128 + l]      = d0 * rstd * g[l] + bb[l];
    H[(size_t)hrow * 128 + 64 + l] = d1 * rstd * g[l + 64] + bb[l + 64];
}

// ---------------- attention v10: fp32, QB=4, Q-tile 32, 2-way key split --------
// grid (79, 8 heads, 2 splits), block 256 (4 waves) -> 1264 blocks (2x waves
// resident vs R9's 632: the fp32 path was latency-bound at 15% occupancy).
// Split z handles key tiles [z*10, z*10+10) of 20 and writes UNNORMALIZED
// partials (acc16, m, l) to PART; attn_merge_kernel combines and normalizes.
// Swizzle r*20 + ((r>>2)&7)*4: hot-loop read rows {4c+kx} -> 8 distinct bank
// quads, conflict-free. No min-waves bound (R8: forced bound -> spill).
__device__ __forceinline__ int kvswz(int r) { return r * 20 + ((r >> 2) & 7) * 4; }

__global__ __launch_bounds__(256) void attn_kernel(
    const float* __restrict__ qkv, float* __restrict__ PART) {
    __shared__ float lds[5184];            // Ks [0,2592), Vs [2592,5184)
    float* Ks = lds;
    float* Vs = lds + 2592;
    const int t = threadIdx.x;
    const int qg = t & 7;
    const int chunk = t >> 3;              // 0..31
    const int head = blockIdx.y;
    const int z = blockIdx.z;
    const int qbase = blockIdx.x * 32 + qg * 4;
    const float SC = 0.25f * 1.4426950408889634f;   // log2e / sqrt(dh)

    float4 q[4][4];
    #pragma unroll
    for (int i = 0; i < 4; ++i) {
        if (qbase + i < SEQ) {
            const float4* qp = (const float4*)&qkv[(size_t)(qbase + i) * 384 + head * 16];
            #pragma unroll
            for (int j = 0; j < 4; ++j) {
                float4 v = qp[j];
                v.x *= SC; v.y *= SC; v.z *= SC; v.w *= SC;
                q[i][j] = v;
            }
        } else {
            #pragma unroll
            for (int j = 0; j < 4; ++j) q[i][j] = make_float4(0.f, 0.f, 0.f, 0.f);
        }
    }
    float m[4] = {-INFINITY, -INFINITY, -INFINITY, -INFINITY};
    float l[4] = {0.f, 0.f, 0.f, 0.f};
    float4 acc[4][4];
    #pragma unroll
    for (int i = 0; i < 4; ++i)
        #pragma unroll
        for (int j = 0; j < 4; ++j) acc[i][j] = make_float4(0.f, 0.f, 0.f, 0.f);

    const int tileA = z * 10, tileB = (z == 0) ? 10 : 20;   // 20 tiles of 128 keys
    for (int ti = tileA; ti < tileB; ++ti) {
        const int tile0 = ti * 128;
        if (ti != tileA) __syncthreads();
        // stage: waves 0-1 -> K rows, waves 2-3 -> V rows
        if (t < 128) {
            int j = tile0 + t;
            if (j < SEQ) {
                const float4* kp = (const float4*)&qkv[(size_t)j * 384 + 128 + head * 16];
                float4* kd = (float4*)&Ks[kvswz(t)];
                kd[0] = kp[0]; kd[1] = kp[1]; kd[2] = kp[2]; kd[3] = kp[3];
            }
        } else {
            int j = tile0 + t - 128;
            if (j < SEQ) {
                const float4* vp = (const float4*)&qkv[(size_t)j * 384 + 256 + head * 16];
                float4* vd = (float4*)&Vs[kvswz(t - 128)];
                vd[0] = vp[0]; vd[1] = vp[1]; vd[2] = vp[2]; vd[3] = vp[3];
            }
        }
        __syncthreads();
        int cnt = SEQ - tile0; if (cnt > 128) cnt = 128;
        const int base = chunk * 4;
        if (base < cnt) {   // cnt is a multiple of 4 -> full key groups always
            float s[4][4];   // [key][query]
            #pragma unroll
            for (int kx = 0; kx < 4; ++kx) {
                const float4* kr = (const float4*)&Ks[kvswz(base + kx)];
                float4 k0 = kr[0], k1 = kr[1], k2 = kr[2], k3 = kr[3];
                #pragma unroll
                for (int qi = 0; qi < 4; ++qi) {
                    float d = q[qi][0].x * k0.x + q[qi][0].y * k0.y + q[qi][0].z * k0.z + q[qi][0].w * k0.w;
                    d += q[qi][1].x * k1.x + q[qi][1].y * k1.y + q[qi][1].z * k1.z + q[qi][1].w * k1.w;
                    d += q[qi][2].x * k2.x + q[qi][2].y * k2.y + q[qi][2].z * k2.z + q[qi][2].w * k2.w;
                    d += q[qi][3].x * k3.x + q[qi][3].y * k3.y + q[qi][3].z * k3.z + q[qi][3].w * k3.w;
                    s[kx][qi] = d;
                }
            }
            float e[4][4];
            #pragma unroll
            for (int qi = 0; qi < 4; ++qi) {
                float gm = fmaxf(fmaxf(s[0][qi], s[1][qi]), fmaxf(s[2][qi], s[3][qi]));
                float nm = fmaxf(m[qi], gm);
                float corr = fexp2(m[qi] - nm);
                float e0 = fexp2(s[0][qi] - nm), e1 = fexp2(s[1][qi] - nm);
                float e2 = fexp2(s[2][qi] - nm), e3 = fexp2(s[3][qi] - nm);
                e[0][qi] = e0; e[1][qi] = e1; e[2][qi] = e2; e[3][qi] = e3;
                l[qi] = fmaf(l[qi], corr, (e0 + e1) + (e2 + e3));
                m[qi] = nm;
                #pragma unroll
                for (int j2 = 0; j2 < 4; ++j2) {
                    acc[qi][j2].x *= corr; acc[qi][j2].y *= corr;
                    acc[qi][j2].z *= corr; acc[qi][j2].w *= corr;
                }
            }
            #pragma unroll
            for (int kx = 0; kx < 4; ++kx) {
                const float4* vr = (const float4*)&Vs[kvswz(base + kx)];
                float4 v0 = vr[0], v1 = vr[1], v2 = vr[2], v3 = vr[3];
                #pragma unroll
                for (int qi = 0; qi < 4; ++qi) {
                    float ee = e[kx][qi];
                    acc[qi][0].x = fmaf(ee, v0.x, acc[qi][0].x);
                    acc[qi][0].y = fmaf(ee, v0.y, acc[qi][0].y);
                    acc[qi][0].z = fmaf(ee, v0.z, acc[qi][0].z);
                    acc[qi][0].w = fmaf(ee, v0.w, acc[qi][0].w);
                    acc[qi][1].x = fmaf(ee, v1.x, acc[qi][1].x);
                    acc[qi][1].y = fmaf(ee, v1.y, acc[qi][1].y);
                    acc[qi][1].z = fmaf(ee, v1.z, acc[qi][1].z);
                    acc[qi][1].w = fmaf(ee, v1.w, acc[qi][1].w);
                    acc[qi][2].x = fmaf(ee, v2.x, acc[qi][2].x);
                    acc[qi][2].y = fmaf(ee, v2.y, acc[qi][2].y);
                    acc[qi][2].z = fmaf(ee, v2.z, acc[qi][2].z);
                    acc[qi][2].w = fmaf(ee, v2.w, acc[qi][2].w);
                    acc[qi][3].x = fmaf(ee, v3.x, acc[qi][3].x);
                    acc[qi][3].y = fmaf(ee, v3.y, acc[qi][3].y);
                    acc[qi][3].z = fmaf(ee, v3.z, acc[qi][3].z);
                    acc[qi][3].w = fmaf(ee, v3.w, acc[qi][3].w);
                }
            }
        }
    }
    __syncthreads();

    // merge the 8 chunk-partials sharing qg within each wave (masks 8,16,32)
    #pragma unroll
    for (int mask = 8; mask <= 32; mask <<= 1) {
        #pragma unroll
        for (int qi = 0; qi < 4; ++qi) {
            float m2 = __shfl_xor(m[qi], mask);
            float l2 = __shfl_xor(l[qi], mask);
            float M = fmaxf(m[qi], m2);
            float c1 = fexp2(m[qi] - M), c2 = fexp2(m2 - M);
            l[qi] = l[qi] * c1 + l2 * c2;
            #pragma unroll
            for (int j2 = 0; j2 < 4; ++j2) {
                float4 o = acc[qi][j2];
                float4 o2;
                o2.x = __shfl_xor(o.x, mask);
                o2.y = __shfl_xor(o.y, mask);
                o2.z = __shfl_xor(o.z, mask);
                o2.w = __shfl_xor(o.w, mask);
                o.x = o.x * c1 + o2.x * c2;
                o.y = o.y * c1 + o2.y * c2;
                o.z = o.z * c1 + o2.z * c2;
                o.w = o.w * c1 + o2.w * c2;
                acc[qi][j2] = o;
            }
            m[qi] = M;
        }
    }
    // 4 wave-partials per (qg,qi): 4 waves * 8 qg * 4 qi = 128 slots
    float* pacc = lds;            // 128*16 = 2048
    float* pm   = lds + 2048;     // 128
    float* pl   = lds + 2176;     // 128
    const int wv = t >> 6;
    if ((t & 63) < 8) {
        #pragma unroll
        for (int qi = 0; qi < 4; ++qi) {
            int slot = (wv * 8 + qg) * 4 + qi;
            float4* dst = (float4*)&pacc[slot * 16];
            dst[0] = acc[qi][0]; dst[1] = acc[qi][1];
            dst[2] = acc[qi][2]; dst[3] = acc[qi][3];
            pm[slot] = m[qi]; pl[slot] = l[qi];
        }
    }
    __syncthreads();
    if (t < 128) {
        const int row = t >> 2;           // 0..31
        const int part = t & 3;
        const int qrow = blockIdx.x * 32 + row;
        if (qrow < SEQ) {
            const int qg2 = row >> 2, qi2 = row & 3;
            float M = -INFINITY;
            #pragma unroll
            for (int w = 0; w < 4; ++w)
                M = fmaxf(M, pm[(w * 8 + qg2) * 4 + qi2]);
            float L = 0.f;
            float4 o = make_float4(0.f, 0.f, 0.f, 0.f);
            #pragma unroll
            for (int w = 0; w < 4; ++w) {
                int slot = (w * 8 + qg2) * 4 + qi2;
                float wgt = fexp2(pm[slot] - M);
                L = fmaf(pl[slot], wgt, L);
                float4 pa = ((const float4*)&pacc[slot * 16])[part];
                o.x = fmaf(pa.x, wgt, o.x); o.y = fmaf(pa.y, wgt, o.y);
                o.z = fmaf(pa.z, wgt, o.z); o.w = fmaf(pa.w, wgt, o.w);
            }
            // write UNNORMALIZED partial (acc16 at [0..15], m at 16, l at 17)
            float* dst = PART + ((size_t)(z * 8 + head) * SEQP + qrow) * 20;
            ((float4*)dst)[part] = o;
            if (part == 0) { dst[16] = M; dst[17] = L; }
        }
    }
}

// ---------------- merge the 2 key-split partials and normalize ------------------
__global__ __launch_bounds__(256) void attn_merge_kernel(
    const float* __restrict__ PART, float* __restrict__ O) {
    int idx = blockIdx.x * 256 + threadIdx.x;     // (head*SEQ + qrow)*4 + part
    if (idx >= 8 * SEQ * 4) return;
    const int part = idx & 3;
    const int rh = idx >> 2;
    const int head = rh / SEQ;
    const int qrow = rh - head * SEQ;
    const float* p0 = PART + ((size_t)(0 * 8 + head) * SEQP + qrow) * 20;
    const float* p1 = PART + ((size_t)(1 * 8 + head) * SEQP + qrow) * 20;
    float m0 = p0[16], l0 = p0[17], m1 = p1[16], l1 = p1[17];
    float M = fmaxf(m0, m1);
    float w0 = fexp2(m0 - M), w1 = fexp2(m1 - M);
    float inv = 1.f / (l0 * w0 + l1 * w1);
    float4 a0 = ((const float4*)p0)[part];
    float4 a1 = ((const float4*)p1)[part];
    float4 o;
    o.x = (a0.x * w0 + a1.x * w1) * inv;
    o.y = (a0.y * w0 + a1.y * w1) * inv;
    o.z = (a0.z * w0 + a1.z * w1) * inv;
    o.w = (a0.w * w0 + a1.w * w1) * inv;
    ((float4*)&O[(size_t)qrow * 128 + head * 16])[part] = o;
}

// ---- region + map_fuse + channel-LN stats (fused) ------------------------------
__global__ __launch_bounds__(256) void region_fuse_stats_kernel(
    const float* __restrict__ sup, const float* __restrict__ qry,
    const float* __restrict__ X, float* __restrict__ fused,
    float* __restrict__ MEAN, float* __restrict__ RSTD) {
    __shared__ float key0[2048];   // 16 x 128
    __shared__ float rfac[100];
    const int b = blockIdx.x;
    const int t = threadIdx.x;
    const float* feat = (b < 25) ? (sup + (size_t)b * 12800) : (qry + (size_t)(b - 25) * 12800);
    for (int i = t; i < 2048; i += 256) key0[i] = X[i];
    __syncthreads();
    if (t < 100) {
        float dots[16];
        #pragma unroll
        for (int mm = 0; mm < 16; ++mm) dots[mm] = 0.f;
        float s = 0.f, ss = 0.f;
        for (int c = 0; c < 128; ++c) {
            float f = feat[c * 100 + t];
            s += f; ss += f * f;
            #pragma unroll
            for (int mm = 0; mm < 16; ++mm) dots[mm] += f * key0[mm * 128 + c];
        }
        float mean16 = 0.f;
        #pragma unroll
        for (int mm = 0; mm < 16; ++mm) mean16 += 1.f / (1.f + expf(-dots[mm] * (1.f / 128.f)));
        float r = mean16 * (1.f / 16.f) + 1.f;
        rfac[t] = r;
        float mr = s * (1.f / 128.f);
        float vr = ss * (1.f / 128.f) - mr * mr;
        MEAN[b * 128 + t] = mr * r;
        RSTD[b * 128 + t] = rsqrtf(vr * r * r + 1e-6f);
    }
    __syncthreads();
    for (int i = t; i < 12800; i += 256)
        fused[(size_t)b * 12800 + i] = feat[i] * rfac[i % 100];
}

// ---------------- 3x3 conv, pad 1, 10x10 images --------------------------------
template<int CIN, bool RELU, bool FUSE_LN>
__global__ __launch_bounds__(256) void conv3x3_kernel(
    const float* __restrict__ in, const float* __restrict__ w,
    const float* __restrict__ MEAN, const float* __restrict__ RSTD,
    const float* __restrict__ g, const float* __restrict__ bb,
    float* __restrict__ out) {
    __shared__ float sin_[32 * 144];
    const int b = blockIdx.x;
    const int base_to = blockIdx.y * 8;
    const int t = threadIdx.x;
    const int h = __builtin_amdgcn_readfirstlane(t >> 7);   // wave-uniform
    const int p = t & 127;
    const int py = p / 10, px = p - py * 10;
    const bool active = p < 100;
    float acc[4] = {0.f, 0.f, 0.f, 0.f};
    for (int cb = 0; cb < CIN; cb += 32) {
        if (cb) __syncthreads();
        for (int i = t; i < 32 * 144; i += 256) {
            int c = i / 144, pos = i - c * 144;
            int y = pos / 12 - 1, x = pos % 12 - 1;
            float v = 0.f;
            if ((unsigned)y < 10u && (unsigned)x < 10u) {
                int pp = y * 10 + x;
                float raw = in[(size_t)b * CIN * 100 + (cb + c) * 100 + pp];
                if (FUSE_LN)
                    v = (raw - MEAN[b * 128 + pp]) * RSTD[b * 128 + pp] * g[cb + c] + bb[cb + c];
                else
                    v = raw;
            }
            sin_[i] = v;
        }
        __syncthreads();
        if (active) {
            const float* wbase = w + ((size_t)(base_to + h * 4) * CIN + cb) * 9;
            for (int c = 0; c < 32; ++c) {
                const float* sp = &sin_[c * 144 + py * 12 + px];
                float pix[9];
                #pragma unroll
                for (int k = 0; k < 9; ++k) pix[k] = sp[(k / 3) * 12 + (k % 3)];
                #pragma unroll
                for (int j = 0; j < 4; ++j) {
                    const float* wq = wbase + ((size_t)j * CIN + c) * 9;
                    #pragma unroll
                    for (int k = 0; k < 9; ++k) acc[j] = fmaf(pix[k], wq[k], acc[j]);
                }
            }
        }
    }
    if (active) {
        #pragma unroll
        for (int j = 0; j < 4; ++j) {
            float v = acc[j];
            if (RELU) v = fmaxf(v, 0.f);
            out[(size_t)b * 3200 + (base_to + h * 4 + j) * 100 + p] = v;
        }
    }
}

// ---------------- final pooling -------------------------------------------------
__global__ __launch_bounds__(256) void rfm_out_kernel(
    const float* __restrict__ conv4, const float* __restrict__ fused, float* __restrict__ out) {
    __shared__ float sig[3200];
    __shared__ float sf[12800];
    const int b = blockIdx.x;
    const int t = threadIdx.x;
    for (int i = t; i < 3200; i += 256) sig[i] = 1.f / (1.f + expf(-conv4[(size_t)b * 3200 + i]));
    for (int i = t; i < 12800; i += 256) sf[i] = fused[(size_t)b * 12800 + i];
    __syncthreads();
    for (int o = t; o < 4096; o += 256) {
        int c = o >> 5, tt = o & 31;
        float acc = 0.f;
        for (int p = 0; p < 100; ++p) acc += sig[tt * 100 + p] * sf[c * 100 + p];
        out[(size_t)b * 4096 + o] = acc * 0.01f;
    }
}

extern "C" void kernel_launch(void* const* d_in, const int* in_sizes, int n_in,
                              void* d_out, int out_size, void* d_ws, size_t ws_size,
                              hipStream_t stream) {
    (void)in_sizes; (void)n_in; (void)out_size; (void)ws_size;
    const float* sup    = (const float*)d_in[0];
    const float* qry    = (const float*)d_in[1];
    const float* td     = (const float*)d_in[2];
    const float* ln1_g  = (const float*)d_in[3];
    const float* ln1_b  = (const float*)d_in[4];
    const float* qkv_w  = (const float*)d_in[5];
    const float* qkv_b  = (const float*)d_in[6];
    const float* out_w  = (const float*)d_in[7];
    const float* out_b  = (const float*)d_in[8];
    const float* ln2_g  = (const float*)d_in[9];
    const float* ln2_b  = (const float*)d_in[10];
    const float* mlp_w1 = (const float*)d_in[11];
    const float* mlp_b1 = (const float*)d_in[12];
    const float* mlp_w2 = (const float*)d_in[13];
    const float* mlp_b2 = (const float*)d_in[14];
    const float* rg     = (const float*)d_in[15];
    const float* rb     = (const float*)d_in[16];
    const float* c1     = (const float*)d_in[17];
    const float* c2     = (const float*)d_in[18];
    const float* c3     = (const float*)d_in[19];
    const float* c4     = (const float*)d_in[20];
    float* out = (float*)d_out;

    // buffers padded to 2520 rows for unguarded 8-row GEMM blocks
    float* ws   = (float*)d_ws;
    float* X    = ws;                  // 322560
    float* H    = X + 322560;          // 322560
    float* QKV  = H + 322560;          // 967680
    float* Obuf = QKV + 967680;        // 322560
    float* MLPH = Obuf + 322560;       // 1290240
    float* FUSED= MLPH + 1290240;      // 1280000
    float* MEAN = FUSED + 1280000;     // 12800
    float* RSTD = MEAN + 12800;        // 12800
    float* CB1  = RSTD + 12800;        // 320000
    float* CB2  = CB1 + 320000;        // 320000
    float* PART = CB2 + 320000;        // 2*8*2520*20 = 806400

    const int SG = (SEQ + 7) / 8;      // 315 blocks
    const int MG = (8 * SEQ * 4 + 255) / 256;   // merge grid

    concat_ln_kernel<<<SEQ, 64, 0, stream>>>(td, sup, ln1_g, ln1_b, X, H);
    for (int i = 0; i < 2; ++i) {
        sgemm_kernel<384, 8, 0, false><<<SG, 384, 0, stream>>>(
            H, qkv_w + (size_t)i * 128 * 384, qkv_b + i * 384, nullptr, QKV, SEQ, 128);
        attn_kernel<<<dim3((SEQ + 31) / 32, 8, 2), 256, 0, stream>>>(QKV, PART);
        attn_merge_kernel<<<MG, 256, 0, stream>>>(PART, Obuf);
        sgemm_ln_kernel<<<SG, 512, 0, stream>>>(
            Obuf, out_w + (size_t)i * 128 * 128, out_b + i * 128, X, X, H,
            ln2_g + i * 128, ln2_b + i * 128, SEQ, 128);
        sgemm_kernel<512, 8, 1, false><<<SG, 512, 0, stream>>>(
            H, mlp_w1 + (size_t)i * 128 * 512, mlp_b1 + i * 512, nullptr, MLPH, SEQ, 128);
        const float* ng = (i == 0) ? ln1_g + 128 : ln1_g;
        const float* nb = (i == 0) ? ln1_b + 128 : ln1_b;
        sgemm_ln_kernel<<<SG, 512, 0, stream>>>(
            MLPH, mlp_w2 + (size_t)i * 512 * 128, mlp_b2 + i * 128, X, X, H,
            ng, nb, SEQ, 512);
    }
    region_fuse_stats_kernel<<<100, 256, 0, stream>>>(sup, qry, X, FUSED, MEAN, RSTD);
    conv3x3_kernel<128, true,  true ><<<dim3(100, 4), 256, 0, stream>>>(FUSED, c1, MEAN, RSTD, rg, rb, CB1);
    conv3x3_kernel< 32, true,  false><<<dim3(100, 4), 256, 0, stream>>>(CB1, c2, nullptr, nullptr, nullptr, nullptr, CB2);
    conv3x3_kernel< 32, true,  false><<<dim3(100, 4), 256, 0, stream>>>(CB2, c3, nullptr, nullptr, nullptr, nullptr, CB1);
    conv3x3_kernel< 32, false, false><<<dim3(100, 4), 256, 0, stream>>>(CB1, c4, nullptr, nullptr, nullptr, nullptr, CB2);
    rfm_out_kernel<<<100, 256, 0, stream>>>(CB2, FUSED, out);
}

// Round 11
// 492.216 us; speedup vs baseline: 2.5729x; 1.1834x over previous
//
#include <hip/hip_runtime.h>
#include <math.h>

#define SEQ 2516
#define SEQP 2520
#define CDIM 128

typedef __attribute__((ext_vector_type(8))) short short8;
typedef __attribute__((ext_vector_type(4))) float f32x4;

__device__ __forceinline__ float gelu_exact(float x) {
    return x * 0.5f * (1.0f + erff(x * 0.7071067811865475f));
}
__device__ __forceinline__ float fexp2(float x) { return __builtin_amdgcn_exp2f(x); }
__device__ __forceinline__ short f2bf(float f) {     // fp32 -> bf16 RNE
    unsigned u = __float_as_uint(f);
    unsigned r = 0x7fffu + ((u >> 16) & 1u);
    return (short)((u + r) >> 16);
}

// ---------------- concat + LN1(layer0): one wave per row ------------------------
__global__ __launch_bounds__(64) void concat_ln_kernel(
    const float* __restrict__ td, const float* __restrict__ sup,
    const float* __restrict__ g, const float* __restrict__ b,
    float* __restrict__ X, float* __restrict__ H) {
    const int row = blockIdx.x;
    const int t = threadIdx.x;
    float x0, x1;
    if (row < 16) {
        x0 = td[row * 128 + t];
        x1 = td[row * 128 + 64 + t];
    } else {
        int r = row - 16;
        int n = r / 100, p = r - n * 100;
        x0 = sup[n * 12800 + t * 100 + p];
        x1 = sup[n * 12800 + (t + 64) * 100 + p];
    }
    X[row * 128 + t] = x0;
    X[row * 128 + 64 + t] = x1;
    float s = x0 + x1;
    for (int off = 32; off > 0; off >>= 1) s += __shfl_down(s, off);
    float mean = __shfl(s, 0) * (1.f / 128.f);
    float d0 = x0 - mean, d1 = x1 - mean;
    float v = d0 * d0 + d1 * d1;
    for (int off = 32; off > 0; off >>= 1) v += __shfl_down(v, off);
    float var = __shfl(v, 0) * (1.f / 128.f);
    float rstd = rsqrtf(var + 1e-5f);
    H[row * 128 + t]      = d0 * rstd * g[t] + b[t];
    H[row * 128 + 64 + t] = d1 * rstd * g[t + 64] + b[t + 64];
}

// ---------------- skinny GEMM: 8 M-rows x N cols per block ----------------------
template<int N, int RPT, int ACT, bool RES>
__global__ __launch_bounds__(N * 8 / RPT) void sgemm_kernel(
    const float* __restrict__ A, const float* __restrict__ W,
    const float* __restrict__ bias, const float* __restrict__ R,
    float* __restrict__ C, int M, int K) {
    const int t = threadIdx.x;
    const int c = t % N;
    const int grp = __builtin_amdgcn_readfirstlane(t / N);
    const int r0 = blockIdx.x * 8 + grp * RPT;
    float acc[RPT];
    #pragma unroll
    for (int i = 0; i < RPT; ++i) acc[i] = 0.f;
    #pragma unroll 4
    for (int k0 = 0; k0 < K; k0 += 4) {
        float w0 = W[(size_t)(k0 + 0) * N + c];
        float w1 = W[(size_t)(k0 + 1) * N + c];
        float w2 = W[(size_t)(k0 + 2) * N + c];
        float w3 = W[(size_t)(k0 + 3) * N + c];
        #pragma unroll
        for (int i = 0; i < RPT; ++i) {
            float4 a4 = *(const float4*)&A[(size_t)(r0 + i) * K + k0];
            acc[i] = fmaf(a4.x, w0, acc[i]);
            acc[i] = fmaf(a4.y, w1, acc[i]);
            acc[i] = fmaf(a4.z, w2, acc[i]);
            acc[i] = fmaf(a4.w, w3, acc[i]);
        }
    }
    float bv = bias[c];
    #pragma unroll
    for (int i = 0; i < RPT; ++i) {
        int row = r0 + i;
        if (row < M) {
            float v = acc[i] + bv;
            if (ACT == 1) v = gelu_exact(v);
            if (RES) v += R[(size_t)row * N + c];
            C[(size_t)row * N + c] = v;
        }
    }
}

// ------- skinny GEMM N=128 + residual + row-LN epilogue (writes C and H) --------
__global__ __launch_bounds__(512) void sgemm_ln_kernel(
    const float* __restrict__ A, const float* __restrict__ W,
    const float* __restrict__ bias, const float* __restrict__ R,
    float* __restrict__ C, float* __restrict__ H,
    const float* __restrict__ g, const float* __restrict__ bb, int M, int K) {
    __shared__ float ln[8][130];
    const int t = threadIdx.x;
    const int c = t & 127;
    const int grp = __builtin_amdgcn_readfirstlane(t >> 7);
    const int r0 = blockIdx.x * 8 + grp * 2;
    float acc0 = 0.f, acc1 = 0.f;
    #pragma unroll 4
    for (int k0 = 0; k0 < K; k0 += 4) {
        float w0 = W[(size_t)(k0 + 0) * 128 + c];
        float w1 = W[(size_t)(k0 + 1) * 128 + c];
        float w2 = W[(size_t)(k0 + 2) * 128 + c];
        float w3 = W[(size_t)(k0 + 3) * 128 + c];
        float4 a0 = *(const float4*)&A[(size_t)(r0 + 0) * K + k0];
        float4 a1 = *(const float4*)&A[(size_t)(r0 + 1) * K + k0];
        acc0 = fmaf(a0.x, w0, acc0); acc0 = fmaf(a0.y, w1, acc0);
        acc0 = fmaf(a0.z, w2, acc0); acc0 = fmaf(a0.w, w3, acc0);
        acc1 = fmaf(a1.x, w0, acc1); acc1 = fmaf(a1.y, w1, acc1);
        acc1 = fmaf(a1.z, w2, acc1); acc1 = fmaf(a1.w, w3, acc1);
    }
    float bv = bias[c];
    float v0 = acc0 + bv + R[(size_t)(r0 + 0) * 128 + c];
    float v1 = acc1 + bv + R[(size_t)(r0 + 1) * 128 + c];
    ln[grp * 2 + 0][c] = v0;
    ln[grp * 2 + 1][c] = v1;
    if (r0 + 0 < M) C[(size_t)(r0 + 0) * 128 + c] = v0;
    if (r0 + 1 < M) C[(size_t)(r0 + 1) * 128 + c] = v1;
    __syncthreads();
    const int wv = t >> 6, l = t & 63;
    float x0 = ln[wv][l], x1 = ln[wv][l + 64];
    float s = x0 + x1;
    for (int off = 32; off > 0; off >>= 1) s += __shfl_down(s, off);
    float mean = __shfl(s, 0) * (1.f / 128.f);
    float d0 = x0 - mean, d1 = x1 - mean;
    float vv = d0 * d0 + d1 * d1;
    for (int off = 32; off > 0; off >>= 1) vv += __shfl_down(vv, off);
    float var = __shfl(vv, 0) * (1.f / 128.f);
    float rstd = rsqrtf(var + 1e-5f);
    const int hrow = blockIdx.x * 8 + wv;
    H[(size_t)hrow * 128 + l]      = d0 * rstd * g[l] + bb[l];
    H[(size_t)hrow * 128 + 64 + l] = d1 * rstd * g[l + 64] + bb[l + 64];
}

// ---------------- attention v11: bf16 MFMA flash, split-K=2 ---------------------
// grid (79, 8 heads, 2 splits), block 128 (2 waves). Each wave owns 16 q-rows
// (Q-frag A-layout: A[m=lane&15][k=quad*8+j], k>=16 zero-padded since dh=16).
// K-tiles of 256 keys staged bf16 in LDS: Ks rows stride 24 shorts (48B,
// 16B-aligned, <=2-way banks), V TRANSPOSED Vt[dim][key] stride 264 shorts.
// Per 32-key step: 2x QK mfma (C-layout scores row=quad*4+reg, col=lane&15),
// cross-lane(16) row-max, exp2, P->LDS (stride 40) -> A-layout read, 1 PV mfma
// (full K=32). Wave-internal P round-trip: no barrier needed.
// Writes unnormalized (acc,m,l) partials to PART; attn_merge_kernel combines.
__global__ __launch_bounds__(128) void attn_kernel(
    const float* __restrict__ qkv, float* __restrict__ PART) {
    __shared__ __align__(16) short sKs[11648];   // Ks 6144 | Vt 4224 | P 2*640
    short* Ks = sKs;
    short* Vt = sKs + 256 * 24;
    const int t = threadIdx.x;
    const int wave = t >> 6, lane = t & 63;
    const int quad = lane >> 4, c16 = lane & 15;
    short* Pw = Vt + 16 * 264 + wave * 16 * 40;
    const int head = blockIdx.y, z = blockIdx.z;
    const int qb = blockIdx.x * 32 + wave * 16;
    const float SC = 0.25f * 1.4426950408889634f;   // log2e / sqrt(dh)

    // Q fragment (A-operand layout), scale folded in, zero-pad k>=16
    short8 qf;
    #pragma unroll
    for (int i = 0; i < 8; ++i) qf[i] = 0;
    if (quad < 2) {
        const int qm = qb + c16;
        if (qm < SEQ) {
            const float4* qp = (const float4*)(qkv + (size_t)qm * 384 + head * 16 + quad * 8);
            float4 qa = qp[0], qc = qp[1];
            qf[0] = f2bf(qa.x * SC); qf[1] = f2bf(qa.y * SC);
            qf[2] = f2bf(qa.z * SC); qf[3] = f2bf(qa.w * SC);
            qf[4] = f2bf(qc.x * SC); qf[5] = f2bf(qc.y * SC);
            qf[6] = f2bf(qc.z * SC); qf[7] = f2bf(qc.w * SC);
        }
    }
    f32x4 oacc = {0.f, 0.f, 0.f, 0.f};
    float m_[4] = {-INFINITY, -INFINITY, -INFINITY, -INFINITY};
    float l_[4] = {0.f, 0.f, 0.f, 0.f};

    const int tA = z * 5, tB = z ? 10 : 5;   // 10 tiles of 256 keys
    for (int ti = tA; ti < tB; ++ti) {
        const int tile0 = ti * 256;
        if (ti != tA) __syncthreads();
        // stage 256 keys with 128 threads (2 each): K rows + V transposed, bf16
        #pragma unroll
        for (int rep = 0; rep < 2; ++rep) {
            const int kk = t + rep * 128;
            const int j = tile0 + kk;
            float4 k0v, k1v, k2v, k3v, v0v, v1v, v2v, v3v;
            if (j < SEQ) {
                const float4* kp = (const float4*)(qkv + (size_t)j * 384 + 128 + head * 16);
                const float4* vp = (const float4*)(qkv + (size_t)j * 384 + 256 + head * 16);
                k0v = kp[0]; k1v = kp[1]; k2v = kp[2]; k3v = kp[3];
                v0v = vp[0]; v1v = vp[1]; v2v = vp[2]; v3v = vp[3];
            } else {
                k0v = k1v = k2v = k3v = make_float4(0.f, 0.f, 0.f, 0.f);
                v0v = v1v = v2v = v3v = make_float4(0.f, 0.f, 0.f, 0.f);
            }
            short8 ka, kb;
            ka[0] = f2bf(k0v.x); ka[1] = f2bf(k0v.y); ka[2] = f2bf(k0v.z); ka[3] = f2bf(k0v.w);
            ka[4] = f2bf(k1v.x); ka[5] = f2bf(k1v.y); ka[6] = f2bf(k1v.z); ka[7] = f2bf(k1v.w);
            kb[0] = f2bf(k2v.x); kb[1] = f2bf(k2v.y); kb[2] = f2bf(k2v.z); kb[3] = f2bf(k2v.w);
            kb[4] = f2bf(k3v.x); kb[5] = f2bf(k3v.y); kb[6] = f2bf(k3v.z); kb[7] = f2bf(k3v.w);
            *(short8*)&Ks[kk * 24]     = ka;
            *(short8*)&Ks[kk * 24 + 8] = kb;
            Vt[ 0 * 264 + kk] = f2bf(v0v.x); Vt[ 1 * 264 + kk] = f2bf(v0v.y);
            Vt[ 2 * 264 + kk] = f2bf(v0v.z); Vt[ 3 * 264 + kk] = f2bf(v0v.w);
            Vt[ 4 * 264 + kk] = f2bf(v1v.x); Vt[ 5 * 264 + kk] = f2bf(v1v.y);
            Vt[ 6 * 264 + kk] = f2bf(v1v.z); Vt[ 7 * 264 + kk] = f2bf(v1v.w);
            Vt[ 8 * 264 + kk] = f2bf(v2v.x); Vt[ 9 * 264 + kk] = f2bf(v2v.y);
            Vt[10 * 264 + kk] = f2bf(v2v.z); Vt[11 * 264 + kk] = f2bf(v2v.w);
            Vt[12 * 264 + kk] = f2bf(v3v.x); Vt[13 * 264 + kk] = f2bf(v3v.y);
            Vt[14 * 264 + kk] = f2bf(v3v.z); Vt[15 * 264 + kk] = f2bf(v3v.w);
        }
        __syncthreads();

        #pragma unroll 2
        for (int st = 0; st < 8; ++st) {
            const int k0 = st * 32;
            short8 kfA, kfB;
            #pragma unroll
            for (int i = 0; i < 8; ++i) { kfA[i] = 0; kfB[i] = 0; }
            if (quad < 2) {
                kfA = *(const short8*)&Ks[(k0 + c16) * 24 + quad * 8];
                kfB = *(const short8*)&Ks[(k0 + 16 + c16) * 24 + quad * 8];
            }
            f32x4 zz = {0.f, 0.f, 0.f, 0.f};
            f32x4 sA = __builtin_amdgcn_mfma_f32_16x16x32_bf16(qf, kfA, zz, 0, 0, 0);
            f32x4 sB = __builtin_amdgcn_mfma_f32_16x16x32_bf16(qf, kfB, zz, 0, 0, 0);
            const int keyA = tile0 + k0 + c16;
            const int keyB = keyA + 16;
            if (keyA >= SEQ) { sA[0] = -1e30f; sA[1] = -1e30f; sA[2] = -1e30f; sA[3] = -1e30f; }
            if (keyB >= SEQ) { sB[0] = -1e30f; sB[1] = -1e30f; sB[2] = -1e30f; sB[3] = -1e30f; }
            #pragma unroll
            for (int r = 0; r < 4; ++r) {
                float v = fmaxf(sA[r], sB[r]);
                v = fmaxf(v, __shfl_xor(v, 1));
                v = fmaxf(v, __shfl_xor(v, 2));
                v = fmaxf(v, __shfl_xor(v, 4));
                v = fmaxf(v, __shfl_xor(v, 8));
                float nm = fmaxf(m_[r], v);
                float corr = fexp2(m_[r] - nm);
                float eA = fexp2(sA[r] - nm);
                float eB = fexp2(sB[r] - nm);
                l_[r] = l_[r] * corr + eA + eB;
                m_[r] = nm;
                oacc[r] *= corr;
                Pw[(quad * 4 + r) * 40 + c16]      = f2bf(eA);
                Pw[(quad * 4 + r) * 40 + 16 + c16] = f2bf(eB);
            }
            short8 pf = *(const short8*)&Pw[c16 * 40 + quad * 8];
            short8 vf = *(const short8*)&Vt[c16 * 264 + k0 + quad * 8];
            oacc = __builtin_amdgcn_mfma_f32_16x16x32_bf16(pf, vf, oacc, 0, 0, 0);
        }
    }
    // epilogue: reduce l across the 16 lanes of each quad-row, write partials
    #pragma unroll
    for (int r = 0; r < 4; ++r) {
        float lr = l_[r];
        lr += __shfl_xor(lr, 1);
        lr += __shfl_xor(lr, 2);
        lr += __shfl_xor(lr, 4);
        lr += __shfl_xor(lr, 8);
        const int qrow = qb + quad * 4 + r;
        if (qrow < SEQ) {
            float* dst = PART + ((size_t)(z * 8 + head) * SEQP + qrow) * 20;
            dst[c16] = oacc[r];
            if (c16 == 0) { dst[16] = m_[r]; dst[17] = lr; }
        }
    }
}

// ---------------- merge the 2 key-split partials and normalize ------------------
__global__ __launch_bounds__(256) void attn_merge_kernel(
    const float* __restrict__ PART, float* __restrict__ O) {
    int idx = blockIdx.x * 256 + threadIdx.x;     // (head*SEQ + qrow)*4 + part
    if (idx >= 8 * SEQ * 4) return;
    const int part = idx & 3;
    const int rh = idx >> 2;
    const int head = rh / SEQ;
    const int qrow = rh - head * SEQ;
    const float* p0 = PART + ((size_t)(0 * 8 + head) * SEQP + qrow) * 20;
    const float* p1 = PART + ((size_t)(1 * 8 + head) * SEQP + qrow) * 20;
    float m0 = p0[16], l0 = p0[17], m1 = p1[16], l1 = p1[17];
    float M = fmaxf(m0, m1);
    float w0 = fexp2(m0 - M), w1 = fexp2(m1 - M);
    float inv = 1.f / (l0 * w0 + l1 * w1);
    float4 a0 = ((const float4*)p0)[part];
    float4 a1 = ((const float4*)p1)[part];
    float4 o;
    o.x = (a0.x * w0 + a1.x * w1) * inv;
    o.y = (a0.y * w0 + a1.y * w1) * inv;
    o.z = (a0.z * w0 + a1.z * w1) * inv;
    o.w = (a0.w * w0 + a1.w * w1) * inv;
    ((float4*)&O[(size_t)qrow * 128 + head * 16])[part] = o;
}

// ---- region + map_fuse + channel-LN stats (fused) ------------------------------
__global__ __launch_bounds__(256) void region_fuse_stats_kernel(
    const float* __restrict__ sup, const float* __restrict__ qry,
    const float* __restrict__ X, float* __restrict__ fused,
    float* __restrict__ MEAN, float* __restrict__ RSTD) {
    __shared__ float key0[2048];   // 16 x 128
    __shared__ float rfac[100];
    const int b = blockIdx.x;
    const int t = threadIdx.x;
    const float* feat = (b < 25) ? (sup + (size_t)b * 12800) : (qry + (size_t)(b - 25) * 12800);
    for (int i = t; i < 2048; i += 256) key0[i] = X[i];
    __syncthreads();
    if (t < 100) {
        float dots[16];
        #pragma unroll
        for (int mm = 0; mm < 16; ++mm) dots[mm] = 0.f;
        float s = 0.f, ss = 0.f;
        for (int c = 0; c < 128; ++c) {
            float f = feat[c * 100 + t];
            s += f; ss += f * f;
            #pragma unroll
            for (int mm = 0; mm < 16; ++mm) dots[mm] += f * key0[mm * 128 + c];
        }
        float mean16 = 0.f;
        #pragma unroll
        for (int mm = 0; mm < 16; ++mm) mean16 += 1.f / (1.f + expf(-dots[mm] * (1.f / 128.f)));
        float r = mean16 * (1.f / 16.f) + 1.f;
        rfac[t] = r;
        float mr = s * (1.f / 128.f);
        float vr = ss * (1.f / 128.f) - mr * mr;
        MEAN[b * 128 + t] = mr * r;
        RSTD[b * 128 + t] = rsqrtf(vr * r * r + 1e-6f);
    }
    __syncthreads();
    for (int i = t; i < 12800; i += 256)
        fused[(size_t)b * 12800 + i] = feat[i] * rfac[i % 100];
}

// ---------------- 3x3 conv, pad 1, 10x10 images --------------------------------
template<int CIN, bool RELU, bool FUSE_LN>
__global__ __launch_bounds__(256) void conv3x3_kernel(
    const float* __restrict__ in, const float* __restrict__ w,
    const float* __restrict__ MEAN, const float* __restrict__ RSTD,
    const float* __restrict__ g, const float* __restrict__ bb,
    float* __restrict__ out) {
    __shared__ float sin_[32 * 144];
    const int b = blockIdx.x;
    const int base_to = blockIdx.y * 8;
    const int t = threadIdx.x;
    const int h = __builtin_amdgcn_readfirstlane(t >> 7);   // wave-uniform
    const int p = t & 127;
    const int py = p / 10, px = p - py * 10;
    const bool active = p < 100;
    float acc[4] = {0.f, 0.f, 0.f, 0.f};
    for (int cb = 0; cb < CIN; cb += 32) {
        if (cb) __syncthreads();
        for (int i = t; i < 32 * 144; i += 256) {
            int c = i / 144, pos = i - c * 144;
            int y = pos / 12 - 1, x = pos % 12 - 1;
            float v = 0.f;
            if ((unsigned)y < 10u && (unsigned)x < 10u) {
                int pp = y * 10 + x;
                float raw = in[(size_t)b * CIN * 100 + (cb + c) * 100 + pp];
                if (FUSE_LN)
                    v = (raw - MEAN[b * 128 + pp]) * RSTD[b * 128 + pp] * g[cb + c] + bb[cb + c];
                else
                    v = raw;
            }
            sin_[i] = v;
        }
        __syncthreads();
        if (active) {
            const float* wbase = w + ((size_t)(base_to + h * 4) * CIN + cb) * 9;
            for (int c = 0; c < 32; ++c) {
                const float* sp = &sin_[c * 144 + py * 12 + px];
                float pix[9];
                #pragma unroll
                for (int k = 0; k < 9; ++k) pix[k] = sp[(k / 3) * 12 + (k % 3)];
                #pragma unroll
                for (int j = 0; j < 4; ++j) {
                    const float* wq = wbase + ((size_t)j * CIN + c) * 9;
                    #pragma unroll
                    for (int k = 0; k < 9; ++k) acc[j] = fmaf(pix[k], wq[k], acc[j]);
                }
            }
        }
    }
    if (active) {
        #pragma unroll
        for (int j = 0; j < 4; ++j) {
            float v = acc[j];
            if (RELU) v = fmaxf(v, 0.f);
            out[(size_t)b * 3200 + (base_to + h * 4 + j) * 100 + p] = v;
        }
    }
}

// ---------------- final pooling -------------------------------------------------
__global__ __launch_bounds__(256) void rfm_out_kernel(
    const float* __restrict__ conv4, const float* __restrict__ fused, float* __restrict__ out) {
    __shared__ float sig[3200];
    __shared__ float sf[12800];
    const int b = blockIdx.x;
    const int t = threadIdx.x;
    for (int i = t; i < 3200; i += 256) sig[i] = 1.f / (1.f + expf(-conv4[(size_t)b * 3200 + i]));
    for (int i = t; i < 12800; i += 256) sf[i] = fused[(size_t)b * 12800 + i];
    __syncthreads();
    for (int o = t; o < 4096; o += 256) {
        int c = o >> 5, tt = o & 31;
        float acc = 0.f;
        for (int p = 0; p < 100; ++p) acc += sig[tt * 100 + p] * sf[c * 100 + p];
        out[(size_t)b * 4096 + o] = acc * 0.01f;
    }
}

extern "C" void kernel_launch(void* const* d_in, const int* in_sizes, int n_in,
                              void* d_out, int out_size, void* d_ws, size_t ws_size,
                              hipStream_t stream) {
    (void)in_sizes; (void)n_in; (void)out_size; (void)ws_size;
    const float* sup    = (const float*)d_in[0];
    const float* qry    = (const float*)d_in[1];
    const float* td     = (const float*)d_in[2];
    const float* ln1_g  = (const float*)d_in[3];
    const float* ln1_b  = (const float*)d_in[4];
    const float* qkv_w  = (const float*)d_in[5];
    const float* qkv_b  = (const float*)d_in[6];
    const float* out_w  = (const float*)d_in[7];
    const float* out_b  = (const float*)d_in[8];
    const float* ln2_g  = (const float*)d_in[9];
    const float* ln2_b  = (const float*)d_in[10];
    const float* mlp_w1 = (const float*)d_in[11];
    const float* mlp_b1 = (const float*)d_in[12];
    const float* mlp_w2 = (const float*)d_in[13];
    const float* mlp_b2 = (const float*)d_in[14];
    const float* rg     = (const float*)d_in[15];
    const float* rb     = (const float*)d_in[16];
    const float* c1     = (const float*)d_in[17];
    const float* c2     = (const float*)d_in[18];
    const float* c3     = (const float*)d_in[19];
    const float* c4     = (const float*)d_in[20];
    float* out = (float*)d_out;

    // buffers padded to 2520 rows for unguarded 8-row GEMM blocks
    float* ws   = (float*)d_ws;
    float* X    = ws;                  // 322560
    float* H    = X + 322560;          // 322560
    float* QKV  = H + 322560;          // 967680
    float* Obuf = QKV + 967680;        // 322560
    float* MLPH = Obuf + 322560;       // 1290240
    float* FUSED= MLPH + 1290240;      // 1280000
    float* MEAN = FUSED + 1280000;     // 12800
    float* RSTD = MEAN + 12800;        // 12800
    float* CB1  = RSTD + 12800;        // 320000
    float* CB2  = CB1 + 320000;        // 320000
    float* PART = CB2 + 320000;        // 2*8*2520*20 = 806400

    const int SG = (SEQ + 7) / 8;      // 315 blocks
    const int MG = (8 * SEQ * 4 + 255) / 256;   // merge grid

    concat_ln_kernel<<<SEQ, 64, 0, stream>>>(td, sup, ln1_g, ln1_b, X, H);
    for (int i = 0; i < 2; ++i) {
        sgemm_kernel<384, 8, 0, false><<<SG, 384, 0, stream>>>(
            H, qkv_w + (size_t)i * 128 * 384, qkv_b + i * 384, nullptr, QKV, SEQ, 128);
        attn_kernel<<<dim3((SEQ + 31) / 32, 8, 2), 128, 0, stream>>>(QKV, PART);
        attn_merge_kernel<<<MG, 256, 0, stream>>>(PART, Obuf);
        sgemm_ln_kernel<<<SG, 512, 0, stream>>>(
            Obuf, out_w + (size_t)i * 128 * 128, out_b + i * 128, X, X, H,
            ln2_g + i * 128, ln2_b + i * 128, SEQ, 128);
        sgemm_kernel<512, 8, 1, false><<<SG, 512, 0, stream>>>(
            H, mlp_w1 + (size_t)i * 128 * 512, mlp_b1 + i * 512, nullptr, MLPH, SEQ, 128);
        const float* ng = (i == 0) ? ln1_g + 128 : ln1_g;
        const float* nb = (i == 0) ? ln1_b + 128 : ln1_b;
        sgemm_ln_kernel<<<SG, 512, 0, stream>>>(
            MLPH, mlp_w2 + (size_t)i * 512 * 128, mlp_b2 + i * 128, X, X, H,
            ng, nb, SEQ, 512);
    }
    region_fuse_stats_kernel<<<100, 256, 0, stream>>>(sup, qry, X, FUSED, MEAN, RSTD);
    conv3x3_kernel<128, true,  true ><<<dim3(100, 4), 256, 0, stream>>>(FUSED, c1, MEAN, RSTD, rg, rb, CB1);
    conv3x3_kernel< 32, true,  false><<<dim3(100, 4), 256, 0, stream>>>(CB1, c2, nullptr, nullptr, nullptr, nullptr, CB2);
    conv3x3_kernel< 32, true,  false><<<dim3(100, 4), 256, 0, stream>>>(CB2, c3, nullptr, nullptr, nullptr, nullptr, CB1);
    conv3x3_kernel< 32, false, false><<<dim3(100, 4), 256, 0, stream>>>(CB1, c4, nullptr, nullptr, nullptr, nullptr, CB2);
    rfm_out_kernel<<<100, 256, 0, stream>>>(CB2, FUSED, out);
}

// Round 12
// 461.256 us; speedup vs baseline: 2.7456x; 1.0671x over previous
//
#include <hip/hip_runtime.h>
#include <math.h>

#define SEQ 2516
#define SEQP 2520
#define CDIM 128

typedef __attribute__((ext_vector_type(8))) short short8;
typedef __attribute__((ext_vector_type(4))) float f32x4;

__device__ __forceinline__ float gelu_exact(float x) {
    return x * 0.5f * (1.0f + erff(x * 0.7071067811865475f));
}
__device__ __forceinline__ float fexp2(float x) { return __builtin_amdgcn_exp2f(x); }
__device__ __forceinline__ short f2bf(float f) {     // fp32 -> bf16 RNE
    unsigned u = __float_as_uint(f);
    unsigned r = 0x7fffu + ((u >> 16) & 1u);
    return (short)((u + r) >> 16);
}

// ---------------- concat + LN1(layer0): one wave per row ------------------------
__global__ __launch_bounds__(64) void concat_ln_kernel(
    const float* __restrict__ td, const float* __restrict__ sup,
    const float* __restrict__ g, const float* __restrict__ b,
    float* __restrict__ X, float* __restrict__ H) {
    const int row = blockIdx.x;
    const int t = threadIdx.x;
    float x0, x1;
    if (row < 16) {
        x0 = td[row * 128 + t];
        x1 = td[row * 128 + 64 + t];
    } else {
        int r = row - 16;
        int n = r / 100, p = r - n * 100;
        x0 = sup[n * 12800 + t * 100 + p];
        x1 = sup[n * 12800 + (t + 64) * 100 + p];
    }
    X[row * 128 + t] = x0;
    X[row * 128 + 64 + t] = x1;
    float s = x0 + x1;
    for (int off = 32; off > 0; off >>= 1) s += __shfl_down(s, off);
    float mean = __shfl(s, 0) * (1.f / 128.f);
    float d0 = x0 - mean, d1 = x1 - mean;
    float v = d0 * d0 + d1 * d1;
    for (int off = 32; off > 0; off >>= 1) v += __shfl_down(v, off);
    float var = __shfl(v, 0) * (1.f / 128.f);
    float rstd = rsqrtf(var + 1e-5f);
    H[row * 128 + t]      = d0 * rstd * g[t] + b[t];
    H[row * 128 + 64 + t] = d1 * rstd * g[t + 64] + b[t + 64];
}

// ---------------- skinny GEMM: 8 M-rows x N cols per block ----------------------
template<int N, int RPT, int ACT, bool RES>
__global__ __launch_bounds__(N * 8 / RPT) void sgemm_kernel(
    const float* __restrict__ A, const float* __restrict__ W,
    const float* __restrict__ bias, const float* __restrict__ R,
    float* __restrict__ C, int M, int K) {
    const int t = threadIdx.x;
    const int c = t % N;
    const int grp = __builtin_amdgcn_readfirstlane(t / N);
    const int r0 = blockIdx.x * 8 + grp * RPT;
    float acc[RPT];
    #pragma unroll
    for (int i = 0; i < RPT; ++i) acc[i] = 0.f;
    #pragma unroll 4
    for (int k0 = 0; k0 < K; k0 += 4) {
        float w0 = W[(size_t)(k0 + 0) * N + c];
        float w1 = W[(size_t)(k0 + 1) * N + c];
        float w2 = W[(size_t)(k0 + 2) * N + c];
        float w3 = W[(size_t)(k0 + 3) * N + c];
        #pragma unroll
        for (int i = 0; i < RPT; ++i) {
            float4 a4 = *(const float4*)&A[(size_t)(r0 + i) * K + k0];
            acc[i] = fmaf(a4.x, w0, acc[i]);
            acc[i] = fmaf(a4.y, w1, acc[i]);
            acc[i] = fmaf(a4.z, w2, acc[i]);
            acc[i] = fmaf(a4.w, w3, acc[i]);
        }
    }
    float bv = bias[c];
    #pragma unroll
    for (int i = 0; i < RPT; ++i) {
        int row = r0 + i;
        if (row < M) {
            float v = acc[i] + bv;
            if (ACT == 1) v = gelu_exact(v);
            if (RES) v += R[(size_t)row * N + c];
            C[(size_t)row * N + c] = v;
        }
    }
}

// ------- skinny GEMM N=128 + residual + row-LN epilogue (writes C and H) --------
__global__ __launch_bounds__(512) void sgemm_ln_kernel(
    const float* __restrict__ A, const float* __restrict__ W,
    const float* __restrict__ bias, const float* __restrict__ R,
    float* __restrict__ C, float* __restrict__ H,
    const float* __restrict__ g, const float* __restrict__ bb, int M, int K) {
    __shared__ float ln[8][130];
    const int t = threadIdx.x;
    const int c = t & 127;
    const int grp = __builtin_amdgcn_readfirstlane(t >> 7);
    const int r0 = blockIdx.x * 8 + grp * 2;
    float acc0 = 0.f, acc1 = 0.f;
    #pragma unroll 4
    for (int k0 = 0; k0 < K; k0 += 4) {
        float w0 = W[(size_t)(k0 + 0) * 128 + c];
        float w1 = W[(size_t)(k0 + 1) * 128 + c];
        float w2 = W[(size_t)(k0 + 2) * 128 + c];
        float w3 = W[(size_t)(k0 + 3) * 128 + c];
        float4 a0 = *(const float4*)&A[(size_t)(r0 + 0) * K + k0];
        float4 a1 = *(const float4*)&A[(size_t)(r0 + 1) * K + k0];
        acc0 = fmaf(a0.x, w0, acc0); acc0 = fmaf(a0.y, w1, acc0);
        acc0 = fmaf(a0.z, w2, acc0); acc0 = fmaf(a0.w, w3, acc0);
        acc1 = fmaf(a1.x, w0, acc1); acc1 = fmaf(a1.y, w1, acc1);
        acc1 = fmaf(a1.z, w2, acc1); acc1 = fmaf(a1.w, w3, acc1);
    }
    float bv = bias[c];
    float v0 = acc0 + bv + R[(size_t)(r0 + 0) * 128 + c];
    float v1 = acc1 + bv + R[(size_t)(r0 + 1) * 128 + c];
    ln[grp * 2 + 0][c] = v0;
    ln[grp * 2 + 1][c] = v1;
    if (r0 + 0 < M) C[(size_t)(r0 + 0) * 128 + c] = v0;
    if (r0 + 1 < M) C[(size_t)(r0 + 1) * 128 + c] = v1;
    __syncthreads();
    const int wv = t >> 6, l = t & 63;
    float x0 = ln[wv][l], x1 = ln[wv][l + 64];
    float s = x0 + x1;
    for (int off = 32; off > 0; off >>= 1) s += __shfl_down(s, off);
    float mean = __shfl(s, 0) * (1.f / 128.f);
    float d0 = x0 - mean, d1 = x1 - mean;
    float vv = d0 * d0 + d1 * d1;
    for (int off = 32; off > 0; off >>= 1) vv += __shfl_down(vv, off);
    float var = __shfl(vv, 0) * (1.f / 128.f);
    float rstd = rsqrtf(var + 1e-5f);
    const int hrow = blockIdx.x * 8 + wv;
    H[(size_t)hrow * 128 + l]      = d0 * rstd * g[l] + bb[l];
    H[(size_t)hrow * 128 + 64 + l] = d1 * rstd * g[l + 64] + bb[l + 64];
}

// ---------------- attention v11: bf16 MFMA flash, split-K=2 ---------------------
__global__ __launch_bounds__(128) void attn_kernel(
    const float* __restrict__ qkv, float* __restrict__ PART) {
    __shared__ __align__(16) short sKs[11648];   // Ks 6144 | Vt 4224 | P 2*640
    short* Ks = sKs;
    short* Vt = sKs + 256 * 24;
    const int t = threadIdx.x;
    const int wave = t >> 6, lane = t & 63;
    const int quad = lane >> 4, c16 = lane & 15;
    short* Pw = Vt + 16 * 264 + wave * 16 * 40;
    const int head = blockIdx.y, z = blockIdx.z;
    const int qb = blockIdx.x * 32 + wave * 16;
    const float SC = 0.25f * 1.4426950408889634f;   // log2e / sqrt(dh)

    short8 qf;
    #pragma unroll
    for (int i = 0; i < 8; ++i) qf[i] = 0;
    if (quad < 2) {
        const int qm = qb + c16;
        if (qm < SEQ) {
            const float4* qp = (const float4*)(qkv + (size_t)qm * 384 + head * 16 + quad * 8);
            float4 qa = qp[0], qc = qp[1];
            qf[0] = f2bf(qa.x * SC); qf[1] = f2bf(qa.y * SC);
            qf[2] = f2bf(qa.z * SC); qf[3] = f2bf(qa.w * SC);
            qf[4] = f2bf(qc.x * SC); qf[5] = f2bf(qc.y * SC);
            qf[6] = f2bf(qc.z * SC); qf[7] = f2bf(qc.w * SC);
        }
    }
    f32x4 oacc = {0.f, 0.f, 0.f, 0.f};
    float m_[4] = {-INFINITY, -INFINITY, -INFINITY, -INFINITY};
    float l_[4] = {0.f, 0.f, 0.f, 0.f};

    const int tA = z * 5, tB = z ? 10 : 5;   // 10 tiles of 256 keys
    for (int ti = tA; ti < tB; ++ti) {
        const int tile0 = ti * 256;
        if (ti != tA) __syncthreads();
        #pragma unroll
        for (int rep = 0; rep < 2; ++rep) {
            const int kk = t + rep * 128;
            const int j = tile0 + kk;
            float4 k0v, k1v, k2v, k3v, v0v, v1v, v2v, v3v;
            if (j < SEQ) {
                const float4* kp = (const float4*)(qkv + (size_t)j * 384 + 128 + head * 16);
                const float4* vp = (const float4*)(qkv + (size_t)j * 384 + 256 + head * 16);
                k0v = kp[0]; k1v = kp[1]; k2v = kp[2]; k3v = kp[3];
                v0v = vp[0]; v1v = vp[1]; v2v = vp[2]; v3v = vp[3];
            } else {
                k0v = k1v = k2v = k3v = make_float4(0.f, 0.f, 0.f, 0.f);
                v0v = v1v = v2v = v3v = make_float4(0.f, 0.f, 0.f, 0.f);
            }
            short8 ka, kb;
            ka[0] = f2bf(k0v.x); ka[1] = f2bf(k0v.y); ka[2] = f2bf(k0v.z); ka[3] = f2bf(k0v.w);
            ka[4] = f2bf(k1v.x); ka[5] = f2bf(k1v.y); ka[6] = f2bf(k1v.z); ka[7] = f2bf(k1v.w);
            kb[0] = f2bf(k2v.x); kb[1] = f2bf(k2v.y); kb[2] = f2bf(k2v.z); kb[3] = f2bf(k2v.w);
            kb[4] = f2bf(k3v.x); kb[5] = f2bf(k3v.y); kb[6] = f2bf(k3v.z); kb[7] = f2bf(k3v.w);
            *(short8*)&Ks[kk * 24]     = ka;
            *(short8*)&Ks[kk * 24 + 8] = kb;
            Vt[ 0 * 264 + kk] = f2bf(v0v.x); Vt[ 1 * 264 + kk] = f2bf(v0v.y);
            Vt[ 2 * 264 + kk] = f2bf(v0v.z); Vt[ 3 * 264 + kk] = f2bf(v0v.w);
            Vt[ 4 * 264 + kk] = f2bf(v1v.x); Vt[ 5 * 264 + kk] = f2bf(v1v.y);
            Vt[ 6 * 264 + kk] = f2bf(v1v.z); Vt[ 7 * 264 + kk] = f2bf(v1v.w);
            Vt[ 8 * 264 + kk] = f2bf(v2v.x); Vt[ 9 * 264 + kk] = f2bf(v2v.y);
            Vt[10 * 264 + kk] = f2bf(v2v.z); Vt[11 * 264 + kk] = f2bf(v2v.w);
            Vt[12 * 264 + kk] = f2bf(v3v.x); Vt[13 * 264 + kk] = f2bf(v3v.y);
            Vt[14 * 264 + kk] = f2bf(v3v.z); Vt[15 * 264 + kk] = f2bf(v3v.w);
        }
        __syncthreads();

        #pragma unroll 2
        for (int st = 0; st < 8; ++st) {
            const int k0 = st * 32;
            short8 kfA, kfB;
            #pragma unroll
            for (int i = 0; i < 8; ++i) { kfA[i] = 0; kfB[i] = 0; }
            if (quad < 2) {
                kfA = *(const short8*)&Ks[(k0 + c16) * 24 + quad * 8];
                kfB = *(const short8*)&Ks[(k0 + 16 + c16) * 24 + quad * 8];
            }
            f32x4 zz = {0.f, 0.f, 0.f, 0.f};
            f32x4 sA = __builtin_amdgcn_mfma_f32_16x16x32_bf16(qf, kfA, zz, 0, 0, 0);
            f32x4 sB = __builtin_amdgcn_mfma_f32_16x16x32_bf16(qf, kfB, zz, 0, 0, 0);
            const int keyA = tile0 + k0 + c16;
            const int keyB = keyA + 16;
            if (keyA >= SEQ) { sA[0] = -1e30f; sA[1] = -1e30f; sA[2] = -1e30f; sA[3] = -1e30f; }
            if (keyB >= SEQ) { sB[0] = -1e30f; sB[1] = -1e30f; sB[2] = -1e30f; sB[3] = -1e30f; }
            #pragma unroll
            for (int r = 0; r < 4; ++r) {
                float v = fmaxf(sA[r], sB[r]);
                v = fmaxf(v, __shfl_xor(v, 1));
                v = fmaxf(v, __shfl_xor(v, 2));
                v = fmaxf(v, __shfl_xor(v, 4));
                v = fmaxf(v, __shfl_xor(v, 8));
                float nm = fmaxf(m_[r], v);
                float corr = fexp2(m_[r] - nm);
                float eA = fexp2(sA[r] - nm);
                float eB = fexp2(sB[r] - nm);
                l_[r] = l_[r] * corr + eA + eB;
                m_[r] = nm;
                oacc[r] *= corr;
                Pw[(quad * 4 + r) * 40 + c16]      = f2bf(eA);
                Pw[(quad * 4 + r) * 40 + 16 + c16] = f2bf(eB);
            }
            short8 pf = *(const short8*)&Pw[c16 * 40 + quad * 8];
            short8 vf = *(const short8*)&Vt[c16 * 264 + k0 + quad * 8];
            oacc = __builtin_amdgcn_mfma_f32_16x16x32_bf16(pf, vf, oacc, 0, 0, 0);
        }
    }
    #pragma unroll
    for (int r = 0; r < 4; ++r) {
        float lr = l_[r];
        lr += __shfl_xor(lr, 1);
        lr += __shfl_xor(lr, 2);
        lr += __shfl_xor(lr, 4);
        lr += __shfl_xor(lr, 8);
        const int qrow = qb + quad * 4 + r;
        if (qrow < SEQ) {
            float* dst = PART + ((size_t)(z * 8 + head) * SEQP + qrow) * 20;
            dst[c16] = oacc[r];
            if (c16 == 0) { dst[16] = m_[r]; dst[17] = lr; }
        }
    }
}

// ---------------- merge the 2 key-split partials and normalize ------------------
__global__ __launch_bounds__(256) void attn_merge_kernel(
    const float* __restrict__ PART, float* __restrict__ O) {
    int idx = blockIdx.x * 256 + threadIdx.x;     // (head*SEQ + qrow)*4 + part
    if (idx >= 8 * SEQ * 4) return;
    const int part = idx & 3;
    const int rh = idx >> 2;
    const int head = rh / SEQ;
    const int qrow = rh - head * SEQ;
    const float* p0 = PART + ((size_t)(0 * 8 + head) * SEQP + qrow) * 20;
    const float* p1 = PART + ((size_t)(1 * 8 + head) * SEQP + qrow) * 20;
    float m0 = p0[16], l0 = p0[17], m1 = p1[16], l1 = p1[17];
    float M = fmaxf(m0, m1);
    float w0 = fexp2(m0 - M), w1 = fexp2(m1 - M);
    float inv = 1.f / (l0 * w0 + l1 * w1);
    float4 a0 = ((const float4*)p0)[part];
    float4 a1 = ((const float4*)p1)[part];
    float4 o;
    o.x = (a0.x * w0 + a1.x * w1) * inv;
    o.y = (a0.y * w0 + a1.y * w1) * inv;
    o.z = (a0.z * w0 + a1.z * w1) * inv;
    o.w = (a0.w * w0 + a1.w * w1) * inv;
    ((float4*)&O[(size_t)qrow * 128 + head * 16])[part] = o;
}

// ---- region + map_fuse + channel-LN stats (fused) ------------------------------
__global__ __launch_bounds__(256) void region_fuse_stats_kernel(
    const float* __restrict__ sup, const float* __restrict__ qry,
    const float* __restrict__ X, float* __restrict__ fused,
    float* __restrict__ MEAN, float* __restrict__ RSTD) {
    __shared__ float key0[2048];   // 16 x 128
    __shared__ float rfac[100];
    const int b = blockIdx.x;
    const int t = threadIdx.x;
    const float* feat = (b < 25) ? (sup + (size_t)b * 12800) : (qry + (size_t)(b - 25) * 12800);
    for (int i = t; i < 2048; i += 256) key0[i] = X[i];
    __syncthreads();
    if (t < 100) {
        float dots[16];
        #pragma unroll
        for (int mm = 0; mm < 16; ++mm) dots[mm] = 0.f;
        float s = 0.f, ss = 0.f;
        for (int c = 0; c < 128; ++c) {
            float f = feat[c * 100 + t];
            s += f; ss += f * f;
            #pragma unroll
            for (int mm = 0; mm < 16; ++mm) dots[mm] += f * key0[mm * 128 + c];
        }
        float mean16 = 0.f;
        #pragma unroll
        for (int mm = 0; mm < 16; ++mm) mean16 += 1.f / (1.f + expf(-dots[mm] * (1.f / 128.f)));
        float r = mean16 * (1.f / 16.f) + 1.f;
        rfac[t] = r;
        float mr = s * (1.f / 128.f);
        float vr = ss * (1.f / 128.f) - mr * mr;
        MEAN[b * 128 + t] = mr * r;
        RSTD[b * 128 + t] = rsqrtf(vr * r * r + 1e-6f);
    }
    __syncthreads();
    for (int i = t; i < 12800; i += 256)
        fused[(size_t)b * 12800 + i] = feat[i] * rfac[i % 100];
}

// ---- conv1 split over input channels: grid (100, 4 to-groups, 4 cin-chunks) ----
// Each z-block convolves its 32-cin chunk (LN fused at staging) and writes an
// fp32 PARTIAL (no relu) to PARTC[z]. conv1_combine sums + relu.
__global__ __launch_bounds__(256) void conv1_split_kernel(
    const float* __restrict__ in, const float* __restrict__ w,
    const float* __restrict__ MEAN, const float* __restrict__ RSTD,
    const float* __restrict__ g, const float* __restrict__ bb,
    float* __restrict__ PARTC) {
    __shared__ float sin_[32 * 144];
    const int b = blockIdx.x;
    const int base_to = blockIdx.y * 8;
    const int cb = blockIdx.z * 32;
    const int t = threadIdx.x;
    const int h = __builtin_amdgcn_readfirstlane(t >> 7);   // wave-uniform
    const int p = t & 127;
    const int py = p / 10, px = p - py * 10;
    const bool active = p < 100;
    float acc[4] = {0.f, 0.f, 0.f, 0.f};
    for (int i = t; i < 32 * 144; i += 256) {
        int c = i / 144, pos = i - c * 144;
        int y = pos / 12 - 1, x = pos % 12 - 1;
        float v = 0.f;
        if ((unsigned)y < 10u && (unsigned)x < 10u) {
            int pp = y * 10 + x;
            float raw = in[(size_t)b * 12800 + (cb + c) * 100 + pp];
            v = (raw - MEAN[b * 128 + pp]) * RSTD[b * 128 + pp] * g[cb + c] + bb[cb + c];
        }
        sin_[i] = v;
    }
    __syncthreads();
    if (active) {
        const float* wbase = w + ((size_t)(base_to + h * 4) * 128 + cb) * 9;
        for (int c = 0; c < 32; ++c) {
            const float* sp = &sin_[c * 144 + py * 12 + px];
            float pix[9];
            #pragma unroll
            for (int k = 0; k < 9; ++k) pix[k] = sp[(k / 3) * 12 + (k % 3)];
            #pragma unroll
            for (int j = 0; j < 4; ++j) {
                const float* wq = wbase + ((size_t)j * 128 + c) * 9;
                #pragma unroll
                for (int k = 0; k < 9; ++k) acc[j] = fmaf(pix[k], wq[k], acc[j]);
            }
        }
        #pragma unroll
        for (int j = 0; j < 4; ++j)
            PARTC[((size_t)blockIdx.z * 100 + b) * 3200 + (base_to + h * 4 + j) * 100 + p] = acc[j];
    }
}

__global__ __launch_bounds__(256) void conv1_combine_kernel(
    const float* __restrict__ PARTC, float* __restrict__ out) {
    int i = blockIdx.x * 256 + threadIdx.x;   // float4 index, 80000 total
    if (i >= 80000) return;
    float4 a = ((const float4*)PARTC)[i];
    float4 b = ((const float4*)(PARTC + 320000))[i];
    float4 c = ((const float4*)(PARTC + 640000))[i];
    float4 d = ((const float4*)(PARTC + 960000))[i];
    float4 o;
    o.x = fmaxf(a.x + b.x + c.x + d.x, 0.f);
    o.y = fmaxf(a.y + b.y + c.y + d.y, 0.f);
    o.z = fmaxf(a.z + b.z + c.z + d.z, 0.f);
    o.w = fmaxf(a.w + b.w + c.w + d.w, 0.f);
    ((float4*)out)[i] = o;
}

// ---------------- 3x3 conv (CIN=32), pad 1, 10x10 images ------------------------
template<int CIN, bool RELU>
__global__ __launch_bounds__(256) void conv3x3_kernel(
    const float* __restrict__ in, const float* __restrict__ w,
    float* __restrict__ out) {
    __shared__ float sin_[32 * 144];
    const int b = blockIdx.x;
    const int base_to = blockIdx.y * 8;
    const int t = threadIdx.x;
    const int h = __builtin_amdgcn_readfirstlane(t >> 7);   // wave-uniform
    const int p = t & 127;
    const int py = p / 10, px = p - py * 10;
    const bool active = p < 100;
    float acc[4] = {0.f, 0.f, 0.f, 0.f};
    for (int i = t; i < 32 * 144; i += 256) {
        int c = i / 144, pos = i - c * 144;
        int y = pos / 12 - 1, x = pos % 12 - 1;
        float v = 0.f;
        if ((unsigned)y < 10u && (unsigned)x < 10u)
            v = in[(size_t)b * CIN * 100 + c * 100 + y * 10 + x];
        sin_[i] = v;
    }
    __syncthreads();
    if (active) {
        const float* wbase = w + ((size_t)(base_to + h * 4) * CIN) * 9;
        for (int c = 0; c < 32; ++c) {
            const float* sp = &sin_[c * 144 + py * 12 + px];
            float pix[9];
            #pragma unroll
            for (int k = 0; k < 9; ++k) pix[k] = sp[(k / 3) * 12 + (k % 3)];
            #pragma unroll
            for (int j = 0; j < 4; ++j) {
                const float* wq = wbase + ((size_t)j * CIN + c) * 9;
                #pragma unroll
                for (int k = 0; k < 9; ++k) acc[j] = fmaf(pix[k], wq[k], acc[j]);
            }
        }
        #pragma unroll
        for (int j = 0; j < 4; ++j) {
            float v = acc[j];
            if (RELU) v = fmaxf(v, 0.f);
            out[(size_t)b * 3200 + (base_to + h * 4 + j) * 100 + p] = v;
        }
    }
}

// ---------------- final pooling -------------------------------------------------
__global__ __launch_bounds__(256) void rfm_out_kernel(
    const float* __restrict__ conv4, const float* __restrict__ fused, float* __restrict__ out) {
    __shared__ float sig[3200];
    __shared__ float sf[12800];
    const int b = blockIdx.x;
    const int t = threadIdx.x;
    for (int i = t; i < 3200; i += 256) sig[i] = 1.f / (1.f + expf(-conv4[(size_t)b * 3200 + i]));
    for (int i = t; i < 12800; i += 256) sf[i] = fused[(size_t)b * 12800 + i];
    __syncthreads();
    for (int o = t; o < 4096; o += 256) {
        int c = o >> 5, tt = o & 31;
        float acc = 0.f;
        for (int p = 0; p < 100; ++p) acc += sig[tt * 100 + p] * sf[c * 100 + p];
        out[(size_t)b * 4096 + o] = acc * 0.01f;
    }
}

extern "C" void kernel_launch(void* const* d_in, const int* in_sizes, int n_in,
                              void* d_out, int out_size, void* d_ws, size_t ws_size,
                              hipStream_t stream) {
    (void)in_sizes; (void)n_in; (void)out_size; (void)ws_size;
    const float* sup    = (const float*)d_in[0];
    const float* qry    = (const float*)d_in[1];
    const float* td     = (const float*)d_in[2];
    const float* ln1_g  = (const float*)d_in[3];
    const float* ln1_b  = (const float*)d_in[4];
    const float* qkv_w  = (const float*)d_in[5];
    const float* qkv_b  = (const float*)d_in[6];
    const float* out_w  = (const float*)d_in[7];
    const float* out_b  = (const float*)d_in[8];
    const float* ln2_g  = (const float*)d_in[9];
    const float* ln2_b  = (const float*)d_in[10];
    const float* mlp_w1 = (const float*)d_in[11];
    const float* mlp_b1 = (const float*)d_in[12];
    const float* mlp_w2 = (const float*)d_in[13];
    const float* mlp_b2 = (const float*)d_in[14];
    const float* rg     = (const float*)d_in[15];
    const float* rb     = (const float*)d_in[16];
    const float* c1     = (const float*)d_in[17];
    const float* c2     = (const float*)d_in[18];
    const float* c3     = (const float*)d_in[19];
    const float* c4     = (const float*)d_in[20];
    float* out = (float*)d_out;

    // buffers padded to 2520 rows for unguarded 8-row GEMM blocks
    float* ws   = (float*)d_ws;
    float* X    = ws;                  // 322560
    float* H    = X + 322560;          // 322560
    float* QKV  = H + 322560;          // 967680
    float* Obuf = QKV + 967680;        // 322560
    float* MLPH = Obuf + 322560;       // 1290240 (dead after transformer; reused as PARTC)
    float* FUSED= MLPH + 1290240;      // 1280000
    float* MEAN = FUSED + 1280000;     // 12800
    float* RSTD = MEAN + 12800;        // 12800
    float* CB1  = RSTD + 12800;        // 320000
    float* CB2  = CB1 + 320000;        // 320000
    float* PART = CB2 + 320000;        // 2*8*2520*20 = 806400
    float* PARTC= MLPH;                // 4*320000 = 1280000 <= 1290240: fits

    const int SG = (SEQ + 7) / 8;      // 315 blocks
    const int MG = (8 * SEQ * 4 + 255) / 256;   // merge grid

    concat_ln_kernel<<<SEQ, 64, 0, stream>>>(td, sup, ln1_g, ln1_b, X, H);
    for (int i = 0; i < 2; ++i) {
        sgemm_kernel<384, 8, 0, false><<<SG, 384, 0, stream>>>(
            H, qkv_w + (size_t)i * 128 * 384, qkv_b + i * 384, nullptr, QKV, SEQ, 128);
        attn_kernel<<<dim3((SEQ + 31) / 32, 8, 2), 128, 0, stream>>>(QKV, PART);
        attn_merge_kernel<<<MG, 256, 0, stream>>>(PART, Obuf);
        sgemm_ln_kernel<<<SG, 512, 0, stream>>>(
            Obuf, out_w + (size_t)i * 128 * 128, out_b + i * 128, X, X, H,
            ln2_g + i * 128, ln2_b + i * 128, SEQ, 128);
        sgemm_kernel<512, 8, 1, false><<<SG, 512, 0, stream>>>(
            H, mlp_w1 + (size_t)i * 128 * 512, mlp_b1 + i * 512, nullptr, MLPH, SEQ, 128);
        const float* ng = (i == 0) ? ln1_g + 128 : ln1_g;
        const float* nb = (i == 0) ? ln1_b + 128 : ln1_b;
        sgemm_ln_kernel<<<SG, 512, 0, stream>>>(
            MLPH, mlp_w2 + (size_t)i * 512 * 128, mlp_b2 + i * 128, X, X, H,
            ng, nb, SEQ, 512);
    }
    region_fuse_stats_kernel<<<100, 256, 0, stream>>>(sup, qry, X, FUSED, MEAN, RSTD);
    conv1_split_kernel<<<dim3(100, 4, 4), 256, 0, stream>>>(FUSED, c1, MEAN, RSTD, rg, rb, PARTC);
    conv1_combine_kernel<<<(80000 + 255) / 256, 256, 0, stream>>>(PARTC, CB1);
    conv3x3_kernel<32, true ><<<dim3(100, 4), 256, 0, stream>>>(CB1, c2, CB2);
    conv3x3_kernel<32, true ><<<dim3(100, 4), 256, 0, stream>>>(CB2, c3, CB1);
    conv3x3_kernel<32, false><<<dim3(100, 4), 256, 0, stream>>>(CB1, c4, CB2);
    rfm_out_kernel<<<100, 256, 0, stream>>>(CB2, FUSED, out);
}

// Round 13
// 454.871 us; speedup vs baseline: 2.7841x; 1.0140x over previous
//
#include <hip/hip_runtime.h>
#include <math.h>

#define SEQ 2516
#define SEQP 2520
#define CDIM 128

typedef __attribute__((ext_vector_type(8))) short short8;
typedef __attribute__((ext_vector_type(4))) float f32x4;

__device__ __forceinline__ float gelu_exact(float x) {
    return x * 0.5f * (1.0f + erff(x * 0.7071067811865475f));
}
__device__ __forceinline__ float fexp2(float x) { return __builtin_amdgcn_exp2f(x); }
__device__ __forceinline__ short f2bf(float f) {     // fp32 -> bf16 RNE
    unsigned u = __float_as_uint(f);
    unsigned r = 0x7fffu + ((u >> 16) & 1u);
    return (short)((u + r) >> 16);
}
__device__ __forceinline__ short f2bf_trunc(float f) {   // for P (e>=0): 1 op
    return (short)(__float_as_uint(f) >> 16);
}

// ---------------- concat + LN1(layer0): one wave per row ------------------------
__global__ __launch_bounds__(64) void concat_ln_kernel(
    const float* __restrict__ td, const float* __restrict__ sup,
    const float* __restrict__ g, const float* __restrict__ b,
    float* __restrict__ X, float* __restrict__ H) {
    const int row = blockIdx.x;
    const int t = threadIdx.x;
    float x0, x1;
    if (row < 16) {
        x0 = td[row * 128 + t];
        x1 = td[row * 128 + 64 + t];
    } else {
        int r = row - 16;
        int n = r / 100, p = r - n * 100;
        x0 = sup[n * 12800 + t * 100 + p];
        x1 = sup[n * 12800 + (t + 64) * 100 + p];
    }
    X[row * 128 + t] = x0;
    X[row * 128 + 64 + t] = x1;
    float s = x0 + x1;
    for (int off = 32; off > 0; off >>= 1) s += __shfl_down(s, off);
    float mean = __shfl(s, 0) * (1.f / 128.f);
    float d0 = x0 - mean, d1 = x1 - mean;
    float v = d0 * d0 + d1 * d1;
    for (int off = 32; off > 0; off >>= 1) v += __shfl_down(v, off);
    float var = __shfl(v, 0) * (1.f / 128.f);
    float rstd = rsqrtf(var + 1e-5f);
    H[row * 128 + t]      = d0 * rstd * g[t] + b[t];
    H[row * 128 + 64 + t] = d1 * rstd * g[t + 64] + b[t + 64];
}

// ---------------- skinny GEMM: 8 M-rows x N cols per block ----------------------
template<int N, int RPT, int ACT, bool RES>
__global__ __launch_bounds__(N * 8 / RPT) void sgemm_kernel(
    const float* __restrict__ A, const float* __restrict__ W,
    const float* __restrict__ bias, const float* __restrict__ R,
    float* __restrict__ C, int M, int K) {
    const int t = threadIdx.x;
    const int c = t % N;
    const int grp = __builtin_amdgcn_readfirstlane(t / N);
    const int r0 = blockIdx.x * 8 + grp * RPT;
    float acc[RPT];
    #pragma unroll
    for (int i = 0; i < RPT; ++i) acc[i] = 0.f;
    #pragma unroll 4
    for (int k0 = 0; k0 < K; k0 += 4) {
        float w0 = W[(size_t)(k0 + 0) * N + c];
        float w1 = W[(size_t)(k0 + 1) * N + c];
        float w2 = W[(size_t)(k0 + 2) * N + c];
        float w3 = W[(size_t)(k0 + 3) * N + c];
        #pragma unroll
        for (int i = 0; i < RPT; ++i) {
            float4 a4 = *(const float4*)&A[(size_t)(r0 + i) * K + k0];
            acc[i] = fmaf(a4.x, w0, acc[i]);
            acc[i] = fmaf(a4.y, w1, acc[i]);
            acc[i] = fmaf(a4.z, w2, acc[i]);
            acc[i] = fmaf(a4.w, w3, acc[i]);
        }
    }
    float bv = bias[c];
    #pragma unroll
    for (int i = 0; i < RPT; ++i) {
        int row = r0 + i;
        if (row < M) {
            float v = acc[i] + bv;
            if (ACT == 1) v = gelu_exact(v);
            if (RES) v += R[(size_t)row * N + c];
            C[(size_t)row * N + c] = v;
        }
    }
}

// ------- skinny GEMM N=128 + residual + row-LN epilogue (writes C and H) --------
__global__ __launch_bounds__(512) void sgemm_ln_kernel(
    const float* __restrict__ A, const float* __restrict__ W,
    const float* __restrict__ bias, const float* __restrict__ R,
    float* __restrict__ C, float* __restrict__ H,
    const float* __restrict__ g, const float* __restrict__ bb, int M, int K) {
    __shared__ float ln[8][130];
    const int t = threadIdx.x;
    const int c = t & 127;
    const int grp = __builtin_amdgcn_readfirstlane(t >> 7);
    const int r0 = blockIdx.x * 8 + grp * 2;
    float acc0 = 0.f, acc1 = 0.f;
    #pragma unroll 4
    for (int k0 = 0; k0 < K; k0 += 4) {
        float w0 = W[(size_t)(k0 + 0) * 128 + c];
        float w1 = W[(size_t)(k0 + 1) * 128 + c];
        float w2 = W[(size_t)(k0 + 2) * 128 + c];
        float w3 = W[(size_t)(k0 + 3) * 128 + c];
        float4 a0 = *(const float4*)&A[(size_t)(r0 + 0) * K + k0];
        float4 a1 = *(const float4*)&A[(size_t)(r0 + 1) * K + k0];
        acc0 = fmaf(a0.x, w0, acc0); acc0 = fmaf(a0.y, w1, acc0);
        acc0 = fmaf(a0.z, w2, acc0); acc0 = fmaf(a0.w, w3, acc0);
        acc1 = fmaf(a1.x, w0, acc1); acc1 = fmaf(a1.y, w1, acc1);
        acc1 = fmaf(a1.z, w2, acc1); acc1 = fmaf(a1.w, w3, acc1);
    }
    float bv = bias[c];
    float v0 = acc0 + bv + R[(size_t)(r0 + 0) * 128 + c];
    float v1 = acc1 + bv + R[(size_t)(r0 + 1) * 128 + c];
    ln[grp * 2 + 0][c] = v0;
    ln[grp * 2 + 1][c] = v1;
    if (r0 + 0 < M) C[(size_t)(r0 + 0) * 128 + c] = v0;
    if (r0 + 1 < M) C[(size_t)(r0 + 1) * 128 + c] = v1;
    __syncthreads();
    const int wv = t >> 6, l = t & 63;
    float x0 = ln[wv][l], x1 = ln[wv][l + 64];
    float s = x0 + x1;
    for (int off = 32; off > 0; off >>= 1) s += __shfl_down(s, off);
    float mean = __shfl(s, 0) * (1.f / 128.f);
    float d0 = x0 - mean, d1 = x1 - mean;
    float vv = d0 * d0 + d1 * d1;
    for (int off = 32; off > 0; off >>= 1) vv += __shfl_down(vv, off);
    float var = __shfl(vv, 0) * (1.f / 128.f);
    float rstd = rsqrtf(var + 1e-5f);
    const int hrow = blockIdx.x * 8 + wv;
    H[(size_t)hrow * 128 + l]      = d0 * rstd * g[l] + bb[l];
    H[(size_t)hrow * 128 + 64 + l] = d1 * rstd * g[l + 64] + bb[l + 64];
}

// ---------------- attention v13: bf16 MFMA flash, TILE-level softmax ------------
// grid (79, 8 heads, 2 splits), block 128 (2 waves), 16 q-rows per wave.
// Per 256-key tile: pass1 = 16 QK mfma into 64 score VGPRs; ONE max-reduce +
// corr/rescale per tile (vs per-32-keys in v11 -> 8x fewer swizzle chains);
// exp2 all + truncating bf16 P -> LDS (stride 264); 8 PV mfma. l_ kept as
// per-lane partial, reduced once at epilogue.
__global__ __launch_bounds__(128) void attn_kernel(
    const float* __restrict__ qkv, float* __restrict__ PART) {
    __shared__ __align__(16) short sKs[18816];  // Ks 6144 | Vt 4224 | P 2*16*264
    short* Ks = sKs;
    short* Vt = sKs + 6144;
    const int t = threadIdx.x;
    const int wave = t >> 6, lane = t & 63;
    const int quad = lane >> 4, c16 = lane & 15;
    short* Pw = sKs + 6144 + 4224 + wave * 16 * 264;
    const int head = blockIdx.y, z = blockIdx.z;
    const int qb = blockIdx.x * 32 + wave * 16;
    const float SC = 0.25f * 1.4426950408889634f;   // log2e / sqrt(dh)

    short8 qf;
    #pragma unroll
    for (int i = 0; i < 8; ++i) qf[i] = 0;
    if (quad < 2) {
        const int qm = qb + c16;
        if (qm < SEQ) {
            const float4* qp = (const float4*)(qkv + (size_t)qm * 384 + head * 16 + quad * 8);
            float4 qa = qp[0], qc = qp[1];
            qf[0] = f2bf(qa.x * SC); qf[1] = f2bf(qa.y * SC);
            qf[2] = f2bf(qa.z * SC); qf[3] = f2bf(qa.w * SC);
            qf[4] = f2bf(qc.x * SC); qf[5] = f2bf(qc.y * SC);
            qf[6] = f2bf(qc.z * SC); qf[7] = f2bf(qc.w * SC);
        }
    }
    f32x4 oacc = {0.f, 0.f, 0.f, 0.f};
    float m_[4] = {-INFINITY, -INFINITY, -INFINITY, -INFINITY};
    float l_[4] = {0.f, 0.f, 0.f, 0.f};   // per-lane partial row-sum

    const int tA = z * 5, tB = z ? 10 : 5;   // 10 tiles of 256 keys
    for (int ti = tA; ti < tB; ++ti) {
        const int tile0 = ti * 256;
        if (ti != tA) __syncthreads();
        #pragma unroll
        for (int rep = 0; rep < 2; ++rep) {
            const int kk = t + rep * 128;
            const int j = tile0 + kk;
            float4 k0v, k1v, k2v, k3v, v0v, v1v, v2v, v3v;
            if (j < SEQ) {
                const float4* kp = (const float4*)(qkv + (size_t)j * 384 + 128 + head * 16);
                const float4* vp = (const float4*)(qkv + (size_t)j * 384 + 256 + head * 16);
                k0v = kp[0]; k1v = kp[1]; k2v = kp[2]; k3v = kp[3];
                v0v = vp[0]; v1v = vp[1]; v2v = vp[2]; v3v = vp[3];
            } else {
                k0v = k1v = k2v = k3v = make_float4(0.f, 0.f, 0.f, 0.f);
                v0v = v1v = v2v = v3v = make_float4(0.f, 0.f, 0.f, 0.f);
            }
            short8 ka, kb;
            ka[0] = f2bf(k0v.x); ka[1] = f2bf(k0v.y); ka[2] = f2bf(k0v.z); ka[3] = f2bf(k0v.w);
            ka[4] = f2bf(k1v.x); ka[5] = f2bf(k1v.y); ka[6] = f2bf(k1v.z); ka[7] = f2bf(k1v.w);
            kb[0] = f2bf(k2v.x); kb[1] = f2bf(k2v.y); kb[2] = f2bf(k2v.z); kb[3] = f2bf(k2v.w);
            kb[4] = f2bf(k3v.x); kb[5] = f2bf(k3v.y); kb[6] = f2bf(k3v.z); kb[7] = f2bf(k3v.w);
            *(short8*)&Ks[kk * 24]     = ka;
            *(short8*)&Ks[kk * 24 + 8] = kb;
            Vt[ 0 * 264 + kk] = f2bf(v0v.x); Vt[ 1 * 264 + kk] = f2bf(v0v.y);
            Vt[ 2 * 264 + kk] = f2bf(v0v.z); Vt[ 3 * 264 + kk] = f2bf(v0v.w);
            Vt[ 4 * 264 + kk] = f2bf(v1v.x); Vt[ 5 * 264 + kk] = f2bf(v1v.y);
            Vt[ 6 * 264 + kk] = f2bf(v1v.z); Vt[ 7 * 264 + kk] = f2bf(v1v.w);
            Vt[ 8 * 264 + kk] = f2bf(v2v.x); Vt[ 9 * 264 + kk] = f2bf(v2v.y);
            Vt[10 * 264 + kk] = f2bf(v2v.z); Vt[11 * 264 + kk] = f2bf(v2v.w);
            Vt[12 * 264 + kk] = f2bf(v3v.x); Vt[13 * 264 + kk] = f2bf(v3v.y);
            Vt[14 * 264 + kk] = f2bf(v3v.z); Vt[15 * 264 + kk] = f2bf(v3v.w);
        }
        __syncthreads();

        // ---- pass 1: all 16 QK mfmas into registers ----
        f32x4 sA[8], sB[8];
        #pragma unroll
        for (int st = 0; st < 8; ++st) {
            const int k0 = st * 32;
            short8 kfA, kfB;
            #pragma unroll
            for (int i = 0; i < 8; ++i) { kfA[i] = 0; kfB[i] = 0; }
            if (quad < 2) {
                kfA = *(const short8*)&Ks[(k0 + c16) * 24 + quad * 8];
                kfB = *(const short8*)&Ks[(k0 + 16 + c16) * 24 + quad * 8];
            }
            f32x4 zz = {0.f, 0.f, 0.f, 0.f};
            sA[st] = __builtin_amdgcn_mfma_f32_16x16x32_bf16(qf, kfA, zz, 0, 0, 0);
            sB[st] = __builtin_amdgcn_mfma_f32_16x16x32_bf16(qf, kfB, zz, 0, 0, 0);
            const bool badA = (tile0 + k0 + c16) >= SEQ;
            const bool badB = (tile0 + k0 + 16 + c16) >= SEQ;
            if (badA) { sA[st][0] = -1e30f; sA[st][1] = -1e30f; sA[st][2] = -1e30f; sA[st][3] = -1e30f; }
            if (badB) { sB[st][0] = -1e30f; sB[st][1] = -1e30f; sB[st][2] = -1e30f; sB[st][3] = -1e30f; }
        }
        // ---- one max-reduce + rescale per tile ----
        #pragma unroll
        for (int r = 0; r < 4; ++r) {
            float v = fmaxf(sA[0][r], sB[0][r]);
            #pragma unroll
            for (int st = 1; st < 8; ++st) v = fmaxf(v, fmaxf(sA[st][r], sB[st][r]));
            v = fmaxf(v, __shfl_xor(v, 1));
            v = fmaxf(v, __shfl_xor(v, 2));
            v = fmaxf(v, __shfl_xor(v, 4));
            v = fmaxf(v, __shfl_xor(v, 8));
            float nm = fmaxf(m_[r], v);
            float corr = fexp2(m_[r] - nm);
            m_[r] = nm;
            oacc[r] *= corr;
            l_[r] *= corr;
        }
        // ---- exp2 + write P (truncating bf16) + accumulate per-lane l ----
        #pragma unroll
        for (int st = 0; st < 8; ++st) {
            #pragma unroll
            for (int r = 0; r < 4; ++r) {
                float eA = fexp2(sA[st][r] - m_[r]);
                float eB = fexp2(sB[st][r] - m_[r]);
                l_[r] += eA + eB;
                Pw[(quad * 4 + r) * 264 + st * 32 + c16]      = f2bf_trunc(eA);
                Pw[(quad * 4 + r) * 264 + st * 32 + 16 + c16] = f2bf_trunc(eB);
            }
        }
        // ---- PV: 8 mfma (wave-internal P round-trip, no barrier needed) ----
        #pragma unroll
        for (int st = 0; st < 8; ++st) {
            short8 pf = *(const short8*)&Pw[c16 * 264 + st * 32 + quad * 8];
            short8 vf = *(const short8*)&Vt[c16 * 264 + st * 32 + quad * 8];
            oacc = __builtin_amdgcn_mfma_f32_16x16x32_bf16(pf, vf, oacc, 0, 0, 0);
        }
    }
    // epilogue: reduce l across the 16 lanes of each quad-row, write partials
    #pragma unroll
    for (int r = 0; r < 4; ++r) {
        float lr = l_[r];
        lr += __shfl_xor(lr, 1);
        lr += __shfl_xor(lr, 2);
        lr += __shfl_xor(lr, 4);
        lr += __shfl_xor(lr, 8);
        const int qrow = qb + quad * 4 + r;
        if (qrow < SEQ) {
            float* dst = PART + ((size_t)(z * 8 + head) * SEQP + qrow) * 20;
            dst[c16] = oacc[r];
            if (c16 == 0) { dst[16] = m_[r]; dst[17] = lr; }
        }
    }
}

// ---------------- merge the 2 key-split partials and normalize ------------------
__global__ __launch_bounds__(256) void attn_merge_kernel(
    const float* __restrict__ PART, float* __restrict__ O) {
    int idx = blockIdx.x * 256 + threadIdx.x;     // (head*SEQ + qrow)*4 + part
    if (idx >= 8 * SEQ * 4) return;
    const int part = idx & 3;
    const int rh = idx >> 2;
    const int head = rh / SEQ;
    const int qrow = rh - head * SEQ;
    const float* p0 = PART + ((size_t)(0 * 8 + head) * SEQP + qrow) * 20;
    const float* p1 = PART + ((size_t)(1 * 8 + head) * SEQP + qrow) * 20;
    float m0 = p0[16], l0 = p0[17], m1 = p1[16], l1 = p1[17];
    float M = fmaxf(m0, m1);
    float w0 = fexp2(m0 - M), w1 = fexp2(m1 - M);
    float inv = 1.f / (l0 * w0 + l1 * w1);
    float4 a0 = ((const float4*)p0)[part];
    float4 a1 = ((const float4*)p1)[part];
    float4 o;
    o.x = (a0.x * w0 + a1.x * w1) * inv;
    o.y = (a0.y * w0 + a1.y * w1) * inv;
    o.z = (a0.z * w0 + a1.z * w1) * inv;
    o.w = (a0.w * w0 + a1.w * w1) * inv;
    ((float4*)&O[(size_t)qrow * 128 + head * 16])[part] = o;
}

// ---- region + map_fuse + channel-LN stats (fused) ------------------------------
__global__ __launch_bounds__(256) void region_fuse_stats_kernel(
    const float* __restrict__ sup, const float* __restrict__ qry,
    const float* __restrict__ X, float* __restrict__ fused,
    float* __restrict__ MEAN, float* __restrict__ RSTD) {
    __shared__ float key0[2048];   // 16 x 128
    __shared__ float rfac[100];
    const int b = blockIdx.x;
    const int t = threadIdx.x;
    const float* feat = (b < 25) ? (sup + (size_t)b * 12800) : (qry + (size_t)(b - 25) * 12800);
    for (int i = t; i < 2048; i += 256) key0[i] = X[i];
    __syncthreads();
    if (t < 100) {
        float dots[16];
        #pragma unroll
        for (int mm = 0; mm < 16; ++mm) dots[mm] = 0.f;
        float s = 0.f, ss = 0.f;
        for (int c = 0; c < 128; ++c) {
            float f = feat[c * 100 + t];
            s += f; ss += f * f;
            #pragma unroll
            for (int mm = 0; mm < 16; ++mm) dots[mm] += f * key0[mm * 128 + c];
        }
        float mean16 = 0.f;
        #pragma unroll
        for (int mm = 0; mm < 16; ++mm) mean16 += 1.f / (1.f + expf(-dots[mm] * (1.f / 128.f)));
        float r = mean16 * (1.f / 16.f) + 1.f;
        rfac[t] = r;
        float mr = s * (1.f / 128.f);
        float vr = ss * (1.f / 128.f) - mr * mr;
        MEAN[b * 128 + t] = mr * r;
        RSTD[b * 128 + t] = rsqrtf(vr * r * r + 1e-6f);
    }
    __syncthreads();
    for (int i = t; i < 12800; i += 256)
        fused[(size_t)b * 12800 + i] = feat[i] * rfac[i % 100];
}

// ---- conv1 split over input channels: grid (100, 4 to-groups, 4 cin-chunks) ----
__global__ __launch_bounds__(256) void conv1_split_kernel(
    const float* __restrict__ in, const float* __restrict__ w,
    const float* __restrict__ MEAN, const float* __restrict__ RSTD,
    const float* __restrict__ g, const float* __restrict__ bb,
    float* __restrict__ PARTC) {
    __shared__ float sin_[32 * 144];
    const int b = blockIdx.x;
    const int base_to = blockIdx.y * 8;
    const int cb = blockIdx.z * 32;
    const int t = threadIdx.x;
    const int h = __builtin_amdgcn_readfirstlane(t >> 7);   // wave-uniform
    const int p = t & 127;
    const int py = p / 10, px = p - py * 10;
    const bool active = p < 100;
    float acc[4] = {0.f, 0.f, 0.f, 0.f};
    for (int i = t; i < 32 * 144; i += 256) {
        int c = i / 144, pos = i - c * 144;
        int y = pos / 12 - 1, x = pos % 12 - 1;
        float v = 0.f;
        if ((unsigned)y < 10u && (unsigned)x < 10u) {
            int pp = y * 10 + x;
            float raw = in[(size_t)b * 12800 + (cb + c) * 100 + pp];
            v = (raw - MEAN[b * 128 + pp]) * RSTD[b * 128 + pp] * g[cb + c] + bb[cb + c];
        }
        sin_[i] = v;
    }
    __syncthreads();
    if (active) {
        const float* wbase = w + ((size_t)(base_to + h * 4) * 128 + cb) * 9;
        for (int c = 0; c < 32; ++c) {
            const float* sp = &sin_[c * 144 + py * 12 + px];
            float pix[9];
            #pragma unroll
            for (int k = 0; k < 9; ++k) pix[k] = sp[(k / 3) * 12 + (k % 3)];
            #pragma unroll
            for (int j = 0; j < 4; ++j) {
                const float* wq = wbase + ((size_t)j * 128 + c) * 9;
                #pragma unroll
                for (int k = 0; k < 9; ++k) acc[j] = fmaf(pix[k], wq[k], acc[j]);
            }
        }
        #pragma unroll
        for (int j = 0; j < 4; ++j)
            PARTC[((size_t)blockIdx.z * 100 + b) * 3200 + (base_to + h * 4 + j) * 100 + p] = acc[j];
    }
}

__global__ __launch_bounds__(256) void conv1_combine_kernel(
    const float* __restrict__ PARTC, float* __restrict__ out) {
    int i = blockIdx.x * 256 + threadIdx.x;   // float4 index, 80000 total
    if (i >= 80000) return;
    float4 a = ((const float4*)PARTC)[i];
    float4 b = ((const float4*)(PARTC + 320000))[i];
    float4 c = ((const float4*)(PARTC + 640000))[i];
    float4 d = ((const float4*)(PARTC + 960000))[i];
    float4 o;
    o.x = fmaxf(a.x + b.x + c.x + d.x, 0.f);
    o.y = fmaxf(a.y + b.y + c.y + d.y, 0.f);
    o.z = fmaxf(a.z + b.z + c.z + d.z, 0.f);
    o.w = fmaxf(a.w + b.w + c.w + d.w, 0.f);
    ((float4*)out)[i] = o;
}

// ------- 3x3 conv (CIN=32), pad 1, grid (100, 8): 4 to-channels per block -------
template<bool RELU>
__global__ __launch_bounds__(256) void conv3x3_to4_kernel(
    const float* __restrict__ in, const float* __restrict__ w,
    float* __restrict__ out) {
    __shared__ float sin_[32 * 144];
    const int b = blockIdx.x;
    const int base_to = blockIdx.y * 4;
    const int t = threadIdx.x;
    const int h = __builtin_amdgcn_readfirstlane(t >> 7);   // wave-uniform
    const int p = t & 127;
    const int py = p / 10, px = p - py * 10;
    const bool active = p < 100;
    float acc[2] = {0.f, 0.f};
    for (int i = t; i < 32 * 144; i += 256) {
        int c = i / 144, pos = i - c * 144;
        int y = pos / 12 - 1, x = pos % 12 - 1;
        float v = 0.f;
        if ((unsigned)y < 10u && (unsigned)x < 10u)
            v = in[(size_t)b * 3200 + c * 100 + y * 10 + x];
        sin_[i] = v;
    }
    __syncthreads();
    if (active) {
        const float* wbase = w + ((size_t)(base_to + h * 2) * 32) * 9;
        for (int c = 0; c < 32; ++c) {
            const float* sp = &sin_[c * 144 + py * 12 + px];
            float pix[9];
            #pragma unroll
            for (int k = 0; k < 9; ++k) pix[k] = sp[(k / 3) * 12 + (k % 3)];
            #pragma unroll
            for (int j = 0; j < 2; ++j) {
                const float* wq = wbase + ((size_t)j * 32 + c) * 9;
                #pragma unroll
                for (int k = 0; k < 9; ++k) acc[j] = fmaf(pix[k], wq[k], acc[j]);
            }
        }
        #pragma unroll
        for (int j = 0; j < 2; ++j) {
            float v = acc[j];
            if (RELU) v = fmaxf(v, 0.f);
            out[(size_t)b * 3200 + (base_to + h * 2 + j) * 100 + p] = v;
        }
    }
}

// ---------------- final pooling -------------------------------------------------
__global__ __launch_bounds__(256) void rfm_out_kernel(
    const float* __restrict__ conv4, const float* __restrict__ fused, float* __restrict__ out) {
    __shared__ float sig[3200];
    __shared__ float sf[12800];
    const int b = blockIdx.x;
    const int t = threadIdx.x;
    for (int i = t; i < 3200; i += 256) sig[i] = 1.f / (1.f + expf(-conv4[(size_t)b * 3200 + i]));
    for (int i = t; i < 12800; i += 256) sf[i] = fused[(size_t)b * 12800 + i];
    __syncthreads();
    for (int o = t; o < 4096; o += 256) {
        int c = o >> 5, tt = o & 31;
        float acc = 0.f;
        for (int p = 0; p < 100; ++p) acc += sig[tt * 100 + p] * sf[c * 100 + p];
        out[(size_t)b * 4096 + o] = acc * 0.01f;
    }
}

extern "C" void kernel_launch(void* const* d_in, const int* in_sizes, int n_in,
                              void* d_out, int out_size, void* d_ws, size_t ws_size,
                              hipStream_t stream) {
    (void)in_sizes; (void)n_in; (void)out_size; (void)ws_size;
    const float* sup    = (const float*)d_in[0];
    const float* qry    = (const float*)d_in[1];
    const float* td     = (const float*)d_in[2];
    const float* ln1_g  = (const float*)d_in[3];
    const float* ln1_b  = (const float*)d_in[4];
    const float* qkv_w  = (const float*)d_in[5];
    const float* qkv_b  = (const float*)d_in[6];
    const float* out_w  = (const float*)d_in[7];
    const float* out_b  = (const float*)d_in[8];
    const float* ln2_g  = (const float*)d_in[9];
    const float* ln2_b  = (const float*)d_in[10];
    const float* mlp_w1 = (const float*)d_in[11];
    const float* mlp_b1 = (const float*)d_in[12];
    const float* mlp_w2 = (const float*)d_in[13];
    const float* mlp_b2 = (const float*)d_in[14];
    const float* rg     = (const float*)d_in[15];
    const float* rb     = (const float*)d_in[16];
    const float* c1     = (const float*)d_in[17];
    const float* c2     = (const float*)d_in[18];
    const float* c3     = (const float*)d_in[19];
    const float* c4     = (const float*)d_in[20];
    float* out = (float*)d_out;

    // buffers padded to 2520 rows for unguarded 8-row GEMM blocks
    float* ws   = (float*)d_ws;
    float* X    = ws;                  // 322560
    float* H    = X + 322560;          // 322560
    float* QKV  = H + 322560;          // 967680
    float* Obuf = QKV + 967680;        // 322560
    float* MLPH = Obuf + 322560;       // 1290240 (dead after transformer; reused as PARTC)
    float* FUSED= MLPH + 1290240;      // 1280000
    float* MEAN = FUSED + 1280000;     // 12800
    float* RSTD = MEAN + 12800;        // 12800
    float* CB1  = RSTD + 12800;        // 320000
    float* CB2  = CB1 + 320000;        // 320000
    float* PART = CB2 + 320000;        // 2*8*2520*20 = 806400
    float* PARTC= MLPH;                // 4*320000 = 1280000 <= 1290240: fits

    const int SG = (SEQ + 7) / 8;      // 315 blocks
    const int MG = (8 * SEQ * 4 + 255) / 256;   // merge grid

    concat_ln_kernel<<<SEQ, 64, 0, stream>>>(td, sup, ln1_g, ln1_b, X, H);
    for (int i = 0; i < 2; ++i) {
        sgemm_kernel<384, 8, 0, false><<<SG, 384, 0, stream>>>(
            H, qkv_w + (size_t)i * 128 * 384, qkv_b + i * 384, nullptr, QKV, SEQ, 128);
        attn_kernel<<<dim3((SEQ + 31) / 32, 8, 2), 128, 0, stream>>>(QKV, PART);
        attn_merge_kernel<<<MG, 256, 0, stream>>>(PART, Obuf);
        sgemm_ln_kernel<<<SG, 512, 0, stream>>>(
            Obuf, out_w + (size_t)i * 128 * 128, out_b + i * 128, X, X, H,
            ln2_g + i * 128, ln2_b + i * 128, SEQ, 128);
        sgemm_kernel<512, 8, 1, false><<<SG, 512, 0, stream>>>(
            H, mlp_w1 + (size_t)i * 128 * 512, mlp_b1 + i * 512, nullptr, MLPH, SEQ, 128);
        const float* ng = (i == 0) ? ln1_g + 128 : ln1_g;
        const float* nb = (i == 0) ? ln1_b + 128 : ln1_b;
        sgemm_ln_kernel<<<SG, 512, 0, stream>>>(
            MLPH, mlp_w2 + (size_t)i * 512 * 128, mlp_b2 + i * 128, X, X, H,
            ng, nb, SEQ, 512);
    }
    region_fuse_stats_kernel<<<100, 256, 0, stream>>>(sup, qry, X, FUSED, MEAN, RSTD);
    conv1_split_kernel<<<dim3(100, 4, 4), 256, 0, stream>>>(FUSED, c1, MEAN, RSTD, rg, rb, PARTC);
    conv1_combine_kernel<<<(80000 + 255) / 256, 256, 0, stream>>>(PARTC, CB1);
    conv3x3_to4_kernel<true ><<<dim3(100, 8), 256, 0, stream>>>(CB1, c2, CB2);
    conv3x3_to4_kernel<true ><<<dim3(100, 8), 256, 0, stream>>>(CB2, c3, CB1);
    conv3x3_to4_kernel<false><<<dim3(100, 8), 256, 0, stream>>>(CB1, c4, CB2);
    rfm_out_kernel<<<100, 256, 0, stream>>>(CB2, FUSED, out);
}

// Round 14
// 387.532 us; speedup vs baseline: 3.2679x; 1.1738x over previous
//
#include <hip/hip_runtime.h>
#include <math.h>

#define SEQ 2516
#define SEQP 2520
#define SEQP2 2560
#define CDIM 128

typedef __attribute__((ext_vector_type(8))) short short8;
typedef __attribute__((ext_vector_type(4))) float f32x4;

__device__ __forceinline__ float gelu_exact(float x) {
    return x * 0.5f * (1.0f + erff(x * 0.7071067811865475f));
}
__device__ __forceinline__ float fexp2(float x) { return __builtin_amdgcn_exp2f(x); }
__device__ __forceinline__ short f2bf(float f) {     // fp32 -> bf16 RNE
    unsigned u = __float_as_uint(f);
    unsigned r = 0x7fffu + ((u >> 16) & 1u);
    return (short)((u + r) >> 16);
}
__device__ __forceinline__ short f2bf_trunc(float f) {   // for P (e>=0): 1 op
    return (short)(__float_as_uint(f) >> 16);
}

// ---------------- concat + LN1(layer0): one wave per row ------------------------
__global__ __launch_bounds__(64) void concat_ln_kernel(
    const float* __restrict__ td, const float* __restrict__ sup,
    const float* __restrict__ g, const float* __restrict__ b,
    float* __restrict__ X, float* __restrict__ H) {
    const int row = blockIdx.x;
    const int t = threadIdx.x;
    float x0, x1;
    if (row < 16) {
        x0 = td[row * 128 + t];
        x1 = td[row * 128 + 64 + t];
    } else {
        int r = row - 16;
        int n = r / 100, p = r - n * 100;
        x0 = sup[n * 12800 + t * 100 + p];
        x1 = sup[n * 12800 + (t + 64) * 100 + p];
    }
    X[row * 128 + t] = x0;
    X[row * 128 + 64 + t] = x1;
    float s = x0 + x1;
    for (int off = 32; off > 0; off >>= 1) s += __shfl_down(s, off);
    float mean = __shfl(s, 0) * (1.f / 128.f);
    float d0 = x0 - mean, d1 = x1 - mean;
    float v = d0 * d0 + d1 * d1;
    for (int off = 32; off > 0; off >>= 1) v += __shfl_down(v, off);
    float var = __shfl(v, 0) * (1.f / 128.f);
    float rstd = rsqrtf(var + 1e-5f);
    H[row * 128 + t]      = d0 * rstd * g[t] + b[t];
    H[row * 128 + 64 + t] = d1 * rstd * g[t + 64] + b[t + 64];
}

// -------- MFMA bf16 GEMM: C = act(A@W + bias); A Mx128 fp32, W 128xN fp32 -------
// block 256 (4 waves), tile 64 rows x 64 cols. W-tile staged transposed bf16 in
// LDS Wt[n][k] (stride 136 shorts, 16B-aligned short8 frags). Layouts HW-
// verified via the attention kernel: A-frag A[m=c16][k=quad*8+j], B-frag
// B[n=c16][k=quad*8+j], C[row=quad*4+r][col=c16]. fp32 accumulate.
template<int ACT>
__global__ __launch_bounds__(256) void mfma_gemm_kernel(
    const float* __restrict__ A, const float* __restrict__ W,
    const float* __restrict__ bias, float* __restrict__ C, int M, int N) {
    __shared__ __align__(16) short Wt[64 * 136];   // 17.4 KB
    const int t = threadIdx.x;
    const int wave = t >> 6, lane = t & 63;
    const int quad = lane >> 4, c16 = lane & 15;
    const int m0 = blockIdx.x * 64;
    const int n0 = blockIdx.y * 64;
    // stage W[0:128][n0:n0+64] -> Wt[n][k] bf16 (coalesced reads, b128 writes)
    #pragma unroll
    for (int pass = 0; pass < 4; ++pass) {
        int idx = t + pass * 256;          // 0..1023
        int n = idx & 63, kc = idx >> 6;   // kc 0..15, 8 k each
        short8 wv;
        #pragma unroll
        for (int j = 0; j < 8; ++j)
            wv[j] = f2bf(W[(size_t)(kc * 8 + j) * N + n0 + n]);
        *(short8*)&Wt[n * 136 + kc * 8] = wv;
    }
    __syncthreads();
    const int am = m0 + wave * 16 + c16;   // A row this lane loads (padded buf)
    f32x4 acc[4];
    #pragma unroll
    for (int i = 0; i < 4; ++i) acc[i] = (f32x4){0.f, 0.f, 0.f, 0.f};
    #pragma unroll
    for (int kk = 0; kk < 4; ++kk) {
        const float4* ap = (const float4*)(A + (size_t)am * 128 + kk * 32 + quad * 8);
        float4 a0 = ap[0], a1 = ap[1];
        short8 af;
        af[0] = f2bf(a0.x); af[1] = f2bf(a0.y); af[2] = f2bf(a0.z); af[3] = f2bf(a0.w);
        af[4] = f2bf(a1.x); af[5] = f2bf(a1.y); af[6] = f2bf(a1.z); af[7] = f2bf(a1.w);
        #pragma unroll
        for (int ns = 0; ns < 4; ++ns) {
            short8 wf = *(const short8*)&Wt[(ns * 16 + c16) * 136 + kk * 32 + quad * 8];
            acc[ns] = __builtin_amdgcn_mfma_f32_16x16x32_bf16(af, wf, acc[ns], 0, 0, 0);
        }
    }
    #pragma unroll
    for (int ns = 0; ns < 4; ++ns) {
        const int n = n0 + ns * 16 + c16;
        float bv = bias[n];
        #pragma unroll
        for (int r = 0; r < 4; ++r) {
            int row = m0 + wave * 16 + quad * 4 + r;
            if (row < M) {
                float v = acc[ns][r] + bv;
                if (ACT == 1) v = gelu_exact(v);
                C[(size_t)row * N + n] = v;
            }
        }
    }
}

// ------- skinny GEMM N=128 + residual + row-LN epilogue (writes C and H) --------
__global__ __launch_bounds__(512) void sgemm_ln_kernel(
    const float* __restrict__ A, const float* __restrict__ W,
    const float* __restrict__ bias, const float* __restrict__ R,
    float* __restrict__ C, float* __restrict__ H,
    const float* __restrict__ g, const float* __restrict__ bb, int M, int K) {
    __shared__ float ln[8][130];
    const int t = threadIdx.x;
    const int c = t & 127;
    const int grp = __builtin_amdgcn_readfirstlane(t >> 7);
    const int r0 = blockIdx.x * 8 + grp * 2;
    float acc0 = 0.f, acc1 = 0.f;
    #pragma unroll 4
    for (int k0 = 0; k0 < K; k0 += 4) {
        float w0 = W[(size_t)(k0 + 0) * 128 + c];
        float w1 = W[(size_t)(k0 + 1) * 128 + c];
        float w2 = W[(size_t)(k0 + 2) * 128 + c];
        float w3 = W[(size_t)(k0 + 3) * 128 + c];
        float4 a0 = *(const float4*)&A[(size_t)(r0 + 0) * K + k0];
        float4 a1 = *(const float4*)&A[(size_t)(r0 + 1) * K + k0];
        acc0 = fmaf(a0.x, w0, acc0); acc0 = fmaf(a0.y, w1, acc0);
        acc0 = fmaf(a0.z, w2, acc0); acc0 = fmaf(a0.w, w3, acc0);
        acc1 = fmaf(a1.x, w0, acc1); acc1 = fmaf(a1.y, w1, acc1);
        acc1 = fmaf(a1.z, w2, acc1); acc1 = fmaf(a1.w, w3, acc1);
    }
    float bv = bias[c];
    float v0 = acc0 + bv + R[(size_t)(r0 + 0) * 128 + c];
    float v1 = acc1 + bv + R[(size_t)(r0 + 1) * 128 + c];
    ln[grp * 2 + 0][c] = v0;
    ln[grp * 2 + 1][c] = v1;
    if (r0 + 0 < M) C[(size_t)(r0 + 0) * 128 + c] = v0;
    if (r0 + 1 < M) C[(size_t)(r0 + 1) * 128 + c] = v1;
    __syncthreads();
    const int wv = t >> 6, l = t & 63;
    float x0 = ln[wv][l], x1 = ln[wv][l + 64];
    float s = x0 + x1;
    for (int off = 32; off > 0; off >>= 1) s += __shfl_down(s, off);
    float mean = __shfl(s, 0) * (1.f / 128.f);
    float d0 = x0 - mean, d1 = x1 - mean;
    float vv = d0 * d0 + d1 * d1;
    for (int off = 32; off > 0; off >>= 1) vv += __shfl_down(vv, off);
    float var = __shfl(vv, 0) * (1.f / 128.f);
    float rstd = rsqrtf(var + 1e-5f);
    const int hrow = blockIdx.x * 8 + wv;
    H[(size_t)hrow * 128 + l]      = d0 * rstd * g[l] + bb[l];
    H[(size_t)hrow * 128 + 64 + l] = d1 * rstd * g[l + 64] + bb[l + 64];
}

// ------- attention v14: bf16 MFMA flash, 128-key tiles, tile-level softmax ------
// grid (79, 8 heads, 2 splits), block 128 (2 waves), 16 q-rows/wave.
// 128-key tiles: 8 QK mfma -> 32 score VGPRs (R13's 256-tile used 64 -> VGPR 88,
// occupancy 14% -> slower). One max-reduce + rescale per tile; truncating bf16
// P; 4 PV mfma. LDS 19.2 KB. l_ per-lane, reduced at epilogue.
__global__ __launch_bounds__(128) void attn_kernel(
    const float* __restrict__ qkv, float* __restrict__ PART) {
    __shared__ __align__(16) short sKs[9600];  // Ks 128*24 | Vt 16*136 | P 2*16*136
    short* Ks = sKs;
    short* Vt = sKs + 3072;
    const int t = threadIdx.x;
    const int wave = t >> 6, lane = t & 63;
    const int quad = lane >> 4, c16 = lane & 15;
    short* Pw = sKs + 3072 + 2176 + wave * 16 * 136;
    const int head = blockIdx.y, z = blockIdx.z;
    const int qb = blockIdx.x * 32 + wave * 16;
    const float SC = 0.25f * 1.4426950408889634f;   // log2e / sqrt(dh)

    short8 qf;
    #pragma unroll
    for (int i = 0; i < 8; ++i) qf[i] = 0;
    if (quad < 2) {
        const int qm = qb + c16;
        if (qm < SEQ) {
            const float4* qp = (const float4*)(qkv + (size_t)qm * 384 + head * 16 + quad * 8);
            float4 qa = qp[0], qc = qp[1];
            qf[0] = f2bf(qa.x * SC); qf[1] = f2bf(qa.y * SC);
            qf[2] = f2bf(qa.z * SC); qf[3] = f2bf(qa.w * SC);
            qf[4] = f2bf(qc.x * SC); qf[5] = f2bf(qc.y * SC);
            qf[6] = f2bf(qc.z * SC); qf[7] = f2bf(qc.w * SC);
        }
    }
    f32x4 oacc = {0.f, 0.f, 0.f, 0.f};
    float m_[4] = {-INFINITY, -INFINITY, -INFINITY, -INFINITY};
    float l_[4] = {0.f, 0.f, 0.f, 0.f};

    const int tA = z * 10, tB = z ? 20 : 10;   // 20 tiles of 128 keys
    for (int ti = tA; ti < tB; ++ti) {
        const int tile0 = ti * 128;
        if (ti != tA) __syncthreads();
        {   // stage 128 keys, 1 per thread: K row + V transposed, bf16
            const int kk = t;
            const int j = tile0 + kk;
            float4 k0v, k1v, k2v, k3v, v0v, v1v, v2v, v3v;
            if (j < SEQ) {
                const float4* kp = (const float4*)(qkv + (size_t)j * 384 + 128 + head * 16);
                const float4* vp = (const float4*)(qkv + (size_t)j * 384 + 256 + head * 16);
                k0v = kp[0]; k1v = kp[1]; k2v = kp[2]; k3v = kp[3];
                v0v = vp[0]; v1v = vp[1]; v2v = vp[2]; v3v = vp[3];
            } else {
                k0v = k1v = k2v = k3v = make_float4(0.f, 0.f, 0.f, 0.f);
                v0v = v1v = v2v = v3v = make_float4(0.f, 0.f, 0.f, 0.f);
            }
            short8 ka, kb;
            ka[0] = f2bf(k0v.x); ka[1] = f2bf(k0v.y); ka[2] = f2bf(k0v.z); ka[3] = f2bf(k0v.w);
            ka[4] = f2bf(k1v.x); ka[5] = f2bf(k1v.y); ka[6] = f2bf(k1v.z); ka[7] = f2bf(k1v.w);
            kb[0] = f2bf(k2v.x); kb[1] = f2bf(k2v.y); kb[2] = f2bf(k2v.z); kb[3] = f2bf(k2v.w);
            kb[4] = f2bf(k3v.x); kb[5] = f2bf(k3v.y); kb[6] = f2bf(k3v.z); kb[7] = f2bf(k3v.w);
            *(short8*)&Ks[kk * 24]     = ka;
            *(short8*)&Ks[kk * 24 + 8] = kb;
            Vt[ 0 * 136 + kk] = f2bf(v0v.x); Vt[ 1 * 136 + kk] = f2bf(v0v.y);
            Vt[ 2 * 136 + kk] = f2bf(v0v.z); Vt[ 3 * 136 + kk] = f2bf(v0v.w);
            Vt[ 4 * 136 + kk] = f2bf(v1v.x); Vt[ 5 * 136 + kk] = f2bf(v1v.y);
            Vt[ 6 * 136 + kk] = f2bf(v1v.z); Vt[ 7 * 136 + kk] = f2bf(v1v.w);
            Vt[ 8 * 136 + kk] = f2bf(v2v.x); Vt[ 9 * 136 + kk] = f2bf(v2v.y);
            Vt[10 * 136 + kk] = f2bf(v2v.z); Vt[11 * 136 + kk] = f2bf(v2v.w);
            Vt[12 * 136 + kk] = f2bf(v3v.x); Vt[13 * 136 + kk] = f2bf(v3v.y);
            Vt[14 * 136 + kk] = f2bf(v3v.z); Vt[15 * 136 + kk] = f2bf(v3v.w);
        }
        __syncthreads();

        // pass 1: 8 QK mfmas -> 32 score VGPRs
        f32x4 sA[4], sB[4];
        #pragma unroll
        for (int st = 0; st < 4; ++st) {
            const int k0 = st * 32;
            short8 kfA, kfB;
            #pragma unroll
            for (int i = 0; i < 8; ++i) { kfA[i] = 0; kfB[i] = 0; }
            if (quad < 2) {
                kfA = *(const short8*)&Ks[(k0 + c16) * 24 + quad * 8];
                kfB = *(const short8*)&Ks[(k0 + 16 + c16) * 24 + quad * 8];
            }
            f32x4 zz = {0.f, 0.f, 0.f, 0.f};
            sA[st] = __builtin_amdgcn_mfma_f32_16x16x32_bf16(qf, kfA, zz, 0, 0, 0);
            sB[st] = __builtin_amdgcn_mfma_f32_16x16x32_bf16(qf, kfB, zz, 0, 0, 0);
            const bool badA = (tile0 + k0 + c16) >= SEQ;
            const bool badB = (tile0 + k0 + 16 + c16) >= SEQ;
            if (badA) { sA[st][0] = -1e30f; sA[st][1] = -1e30f; sA[st][2] = -1e30f; sA[st][3] = -1e30f; }
            if (badB) { sB[st][0] = -1e30f; sB[st][1] = -1e30f; sB[st][2] = -1e30f; sB[st][3] = -1e30f; }
        }
        // one max-reduce + rescale per tile
        #pragma unroll
        for (int r = 0; r < 4; ++r) {
            float v = fmaxf(sA[0][r], sB[0][r]);
            #pragma unroll
            for (int st = 1; st < 4; ++st) v = fmaxf(v, fmaxf(sA[st][r], sB[st][r]));
            v = fmaxf(v, __shfl_xor(v, 1));
            v = fmaxf(v, __shfl_xor(v, 2));
            v = fmaxf(v, __shfl_xor(v, 4));
            v = fmaxf(v, __shfl_xor(v, 8));
            float nm = fmaxf(m_[r], v);
            float corr = fexp2(m_[r] - nm);
            m_[r] = nm;
            oacc[r] *= corr;
            l_[r] *= corr;
        }
        // exp2 + write P (truncating bf16) + per-lane l
        #pragma unroll
        for (int st = 0; st < 4; ++st) {
            #pragma unroll
            for (int r = 0; r < 4; ++r) {
                float eA = fexp2(sA[st][r] - m_[r]);
                float eB = fexp2(sB[st][r] - m_[r]);
                l_[r] += eA + eB;
                Pw[(quad * 4 + r) * 136 + st * 32 + c16]      = f2bf_trunc(eA);
                Pw[(quad * 4 + r) * 136 + st * 32 + 16 + c16] = f2bf_trunc(eB);
            }
        }
        // PV: 4 mfma (wave-internal P round-trip, no barrier)
        #pragma unroll
        for (int st = 0; st < 4; ++st) {
            short8 pf = *(const short8*)&Pw[c16 * 136 + st * 32 + quad * 8];
            short8 vf = *(const short8*)&Vt[c16 * 136 + st * 32 + quad * 8];
            oacc = __builtin_amdgcn_mfma_f32_16x16x32_bf16(pf, vf, oacc, 0, 0, 0);
        }
    }
    // epilogue: reduce l across the 16 lanes of each quad-row, write partials
    #pragma unroll
    for (int r = 0; r < 4; ++r) {
        float lr = l_[r];
        lr += __shfl_xor(lr, 1);
        lr += __shfl_xor(lr, 2);
        lr += __shfl_xor(lr, 4);
        lr += __shfl_xor(lr, 8);
        const int qrow = qb + quad * 4 + r;
        if (qrow < SEQ) {
            float* dst = PART + ((size_t)(z * 8 + head) * SEQP + qrow) * 20;
            dst[c16] = oacc[r];
            if (c16 == 0) { dst[16] = m_[r]; dst[17] = lr; }
        }
    }
}

// ---------------- merge the 2 key-split partials and normalize ------------------
__global__ __launch_bounds__(256) void attn_merge_kernel(
    const float* __restrict__ PART, float* __restrict__ O) {
    int idx = blockIdx.x * 256 + threadIdx.x;     // (head*SEQ + qrow)*4 + part
    if (idx >= 8 * SEQ * 4) return;
    const int part = idx & 3;
    const int rh = idx >> 2;
    const int head = rh / SEQ;
    const int qrow = rh - head * SEQ;
    const float* p0 = PART + ((size_t)(0 * 8 + head) * SEQP + qrow) * 20;
    const float* p1 = PART + ((size_t)(1 * 8 + head) * SEQP + qrow) * 20;
    float m0 = p0[16], l0 = p0[17], m1 = p1[16], l1 = p1[17];
    float M = fmaxf(m0, m1);
    float w0 = fexp2(m0 - M), w1 = fexp2(m1 - M);
    float inv = 1.f / (l0 * w0 + l1 * w1);
    float4 a0 = ((const float4*)p0)[part];
    float4 a1 = ((const float4*)p1)[part];
    float4 o;
    o.x = (a0.x * w0 + a1.x * w1) * inv;
    o.y = (a0.y * w0 + a1.y * w1) * inv;
    o.z = (a0.z * w0 + a1.z * w1) * inv;
    o.w = (a0.w * w0 + a1.w * w1) * inv;
    ((float4*)&O[(size_t)qrow * 128 + head * 16])[part] = o;
}

// ---- region + map_fuse + channel-LN stats (fused) ------------------------------
__global__ __launch_bounds__(256) void region_fuse_stats_kernel(
    const float* __restrict__ sup, const float* __restrict__ qry,
    const float* __restrict__ X, float* __restrict__ fused,
    float* __restrict__ MEAN, float* __restrict__ RSTD) {
    __shared__ float key0[2048];   // 16 x 128
    __shared__ float rfac[100];
    const int b = blockIdx.x;
    const int t = threadIdx.x;
    const float* feat = (b < 25) ? (sup + (size_t)b * 12800) : (qry + (size_t)(b - 25) * 12800);
    for (int i = t; i < 2048; i += 256) key0[i] = X[i];
    __syncthreads();
    if (t < 100) {
        float dots[16];
        #pragma unroll
        for (int mm = 0; mm < 16; ++mm) dots[mm] = 0.f;
        float s = 0.f, ss = 0.f;
        for (int c = 0; c < 128; ++c) {
            float f = feat[c * 100 + t];
            s += f; ss += f * f;
            #pragma unroll
            for (int mm = 0; mm < 16; ++mm) dots[mm] += f * key0[mm * 128 + c];
        }
        float mean16 = 0.f;
        #pragma unroll
        for (int mm = 0; mm < 16; ++mm) mean16 += 1.f / (1.f + expf(-dots[mm] * (1.f / 128.f)));
        float r = mean16 * (1.f / 16.f) + 1.f;
        rfac[t] = r;
        float mr = s * (1.f / 128.f);
        float vr = ss * (1.f / 128.f) - mr * mr;
        MEAN[b * 128 + t] = mr * r;
        RSTD[b * 128 + t] = rsqrtf(vr * r * r + 1e-6f);
    }
    __syncthreads();
    for (int i = t; i < 12800; i += 256)
        fused[(size_t)b * 12800 + i] = feat[i] * rfac[i % 100];
}

// ---- conv1 split over input channels: grid (100, 4 to-groups, 4 cin-chunks) ----
__global__ __launch_bounds__(256) void conv1_split_kernel(
    const float* __restrict__ in, const float* __restrict__ w,
    const float* __restrict__ MEAN, const float* __restrict__ RSTD,
    const float* __restrict__ g, const float* __restrict__ bb,
    float* __restrict__ PARTC) {
    __shared__ float sin_[32 * 144];
    const int b = blockIdx.x;
    const int base_to = blockIdx.y * 8;
    const int cb = blockIdx.z * 32;
    const int t = threadIdx.x;
    const int h = __builtin_amdgcn_readfirstlane(t >> 7);   // wave-uniform
    const int p = t & 127;
    const int py = p / 10, px = p - py * 10;
    const bool active = p < 100;
    float acc[4] = {0.f, 0.f, 0.f, 0.f};
    for (int i = t; i < 32 * 144; i += 256) {
        int c = i / 144, pos = i - c * 144;
        int y = pos / 12 - 1, x = pos % 12 - 1;
        float v = 0.f;
        if ((unsigned)y < 10u && (unsigned)x < 10u) {
            int pp = y * 10 + x;
            float raw = in[(size_t)b * 12800 + (cb + c) * 100 + pp];
            v = (raw - MEAN[b * 128 + pp]) * RSTD[b * 128 + pp] * g[cb + c] + bb[cb + c];
        }
        sin_[i] = v;
    }
    __syncthreads();
    if (active) {
        const float* wbase = w + ((size_t)(base_to + h * 4) * 128 + cb) * 9;
        for (int c = 0; c < 32; ++c) {
            const float* sp = &sin_[c * 144 + py * 12 + px];
            float pix[9];
            #pragma unroll
            for (int k = 0; k < 9; ++k) pix[k] = sp[(k / 3) * 12 + (k % 3)];
            #pragma unroll
            for (int j = 0; j < 4; ++j) {
                const float* wq = wbase + ((size_t)j * 128 + c) * 9;
                #pragma unroll
                for (int k = 0; k < 9; ++k) acc[j] = fmaf(pix[k], wq[k], acc[j]);
            }
        }
        #pragma unroll
        for (int j = 0; j < 4; ++j)
            PARTC[((size_t)blockIdx.z * 100 + b) * 3200 + (base_to + h * 4 + j) * 100 + p] = acc[j];
    }
}

__global__ __launch_bounds__(256) void conv1_combine_kernel(
    const float* __restrict__ PARTC, float* __restrict__ out) {
    int i = blockIdx.x * 256 + threadIdx.x;   // float4 index, 80000 total
    if (i >= 80000) return;
    float4 a = ((const float4*)PARTC)[i];
    float4 b = ((const float4*)(PARTC + 320000))[i];
    float4 c = ((const float4*)(PARTC + 640000))[i];
    float4 d = ((const float4*)(PARTC + 960000))[i];
    float4 o;
    o.x = fmaxf(a.x + b.x + c.x + d.x, 0.f);
    o.y = fmaxf(a.y + b.y + c.y + d.y, 0.f);
    o.z = fmaxf(a.z + b.z + c.z + d.z, 0.f);
    o.w = fmaxf(a.w + b.w + c.w + d.w, 0.f);
    ((float4*)out)[i] = o;
}

// ------- 3x3 conv (CIN=32), pad 1, grid (100, 8): 4 to-channels per block -------
template<bool RELU>
__global__ __launch_bounds__(256) void conv3x3_to4_kernel(
    const float* __restrict__ in, const float* __restrict__ w,
    float* __restrict__ out) {
    __shared__ float sin_[32 * 144];
    const int b = blockIdx.x;
    const int base_to = blockIdx.y * 4;
    const int t = threadIdx.x;
    const int h = __builtin_amdgcn_readfirstlane(t >> 7);   // wave-uniform
    const int p = t & 127;
    const int py = p / 10, px = p - py * 10;
    const bool active = p < 100;
    float acc[2] = {0.f, 0.f};
    for (int i = t; i < 32 * 144; i += 256) {
        int c = i / 144, pos = i - c * 144;
        int y = pos / 12 - 1, x = pos % 12 - 1;
        float v = 0.f;
        if ((unsigned)y < 10u && (unsigned)x < 10u)
            v = in[(size_t)b * 3200 + c * 100 + y * 10 + x];
        sin_[i] = v;
    }
    __syncthreads();
    if (active) {
        const float* wbase = w + ((size_t)(base_to + h * 2) * 32) * 9;
        for (int c = 0; c < 32; ++c) {
            const float* sp = &sin_[c * 144 + py * 12 + px];
            float pix[9];
            #pragma unroll
            for (int k = 0; k < 9; ++k) pix[k] = sp[(k / 3) * 12 + (k % 3)];
            #pragma unroll
            for (int j = 0; j < 2; ++j) {
                const float* wq = wbase + ((size_t)j * 32 + c) * 9;
                #pragma unroll
                for (int k = 0; k < 9; ++k) acc[j] = fmaf(pix[k], wq[k], acc[j]);
            }
        }
        #pragma unroll
        for (int j = 0; j < 2; ++j) {
            float v = acc[j];
            if (RELU) v = fmaxf(v, 0.f);
            out[(size_t)b * 3200 + (base_to + h * 2 + j) * 100 + p] = v;
        }
    }
}

// ---------------- final pooling -------------------------------------------------
__global__ __launch_bounds__(256) void rfm_out_kernel(
    const float* __restrict__ conv4, const float* __restrict__ fused, float* __restrict__ out) {
    __shared__ float sig[3200];
    __shared__ float sf[12800];
    const int b = blockIdx.x;
    const int t = threadIdx.x;
    for (int i = t; i < 3200; i += 256) sig[i] = 1.f / (1.f + expf(-conv4[(size_t)b * 3200 + i]));
    for (int i = t; i < 12800; i += 256) sf[i] = fused[(size_t)b * 12800 + i];
    __syncthreads();
    for (int o = t; o < 4096; o += 256) {
        int c = o >> 5, tt = o & 31;
        float acc = 0.f;
        for (int p = 0; p < 100; ++p) acc += sig[tt * 100 + p] * sf[c * 100 + p];
        out[(size_t)b * 4096 + o] = acc * 0.01f;
    }
}

extern "C" void kernel_launch(void* const* d_in, const int* in_sizes, int n_in,
                              void* d_out, int out_size, void* d_ws, size_t ws_size,
                              hipStream_t stream) {
    (void)in_sizes; (void)n_in; (void)out_size; (void)ws_size;
    const float* sup    = (const float*)d_in[0];
    const float* qry    = (const float*)d_in[1];
    const float* td     = (const float*)d_in[2];
    const float* ln1_g  = (const float*)d_in[3];
    const float* ln1_b  = (const float*)d_in[4];
    const float* qkv_w  = (const float*)d_in[5];
    const float* qkv_b  = (const float*)d_in[6];
    const float* out_w  = (const float*)d_in[7];
    const float* out_b  = (const float*)d_in[8];
    const float* ln2_g  = (const float*)d_in[9];
    const float* ln2_b  = (const float*)d_in[10];
    const float* mlp_w1 = (const float*)d_in[11];
    const float* mlp_b1 = (const float*)d_in[12];
    const float* mlp_w2 = (const float*)d_in[13];
    const float* mlp_b2 = (const float*)d_in[14];
    const float* rg     = (const float*)d_in[15];
    const float* rb     = (const float*)d_in[16];
    const float* c1     = (const float*)d_in[17];
    const float* c2     = (const float*)d_in[18];
    const float* c3     = (const float*)d_in[19];
    const float* c4     = (const float*)d_in[20];
    float* out = (float*)d_out;

    // transformer buffers padded to 2560 rows (64-row MFMA M-tiles read unguarded)
    float* ws   = (float*)d_ws;
    float* X    = ws;                  // 2560*128 = 327680
    float* H    = X + 327680;          // 327680
    float* QKV  = H + 327680;          // 2560*384 = 983040
    float* Obuf = QKV + 983040;        // 327680
    float* MLPH = Obuf + 327680;       // 2560*512 = 1310720 (reused as PARTC)
    float* FUSED= MLPH + 1310720;      // 1280000
    float* MEAN = FUSED + 1280000;     // 12800
    float* RSTD = MEAN + 12800;        // 12800
    float* CB1  = RSTD + 12800;        // 320000
    float* CB2  = CB1 + 320000;        // 320000
    float* PART = CB2 + 320000;        // 2*8*2520*20 = 806400
    float* PARTC= MLPH;                // 4*320000 = 1280000 <= 1310720: fits

    const int SG = (SEQ + 7) / 8;      // 315 blocks
    const int MG = (8 * SEQ * 4 + 255) / 256;   // merge grid
    const int MT = (SEQ + 63) / 64;    // 40 M-tiles for MFMA GEMMs

    concat_ln_kernel<<<SEQ, 64, 0, stream>>>(td, sup, ln1_g, ln1_b, X, H);
    for (int i = 0; i < 2; ++i) {
        mfma_gemm_kernel<0><<<dim3(MT, 6), 256, 0, stream>>>(
            H, qkv_w + (size_t)i * 128 * 384, qkv_b + i * 384, QKV, SEQ, 384);
        attn_kernel<<<dim3((SEQ + 31) / 32, 8, 2), 128, 0, stream>>>(QKV, PART);
        attn_merge_kernel<<<MG, 256, 0, stream>>>(PART, Obuf);
        sgemm_ln_kernel<<<SG, 512, 0, stream>>>(
            Obuf, out_w + (size_t)i * 128 * 128, out_b + i * 128, X, X, H,
            ln2_g + i * 128, ln2_b + i * 128, SEQ, 128);
        mfma_gemm_kernel<1><<<dim3(MT, 8), 256, 0, stream>>>(
            H, mlp_w1 + (size_t)i * 128 * 512, mlp_b1 + i * 512, MLPH, SEQ, 512);
        const float* ng = (i == 0) ? ln1_g + 128 : ln1_g;
        const float* nb = (i == 0) ? ln1_b + 128 : ln1_b;
        sgemm_ln_kernel<<<SG, 512, 0, stream>>>(
            MLPH, mlp_w2 + (size_t)i * 512 * 128, mlp_b2 + i * 128, X, X, H,
            ng, nb, SEQ, 512);
    }
    region_fuse_stats_kernel<<<100, 256, 0, stream>>>(sup, qry, X, FUSED, MEAN, RSTD);
    conv1_split_kernel<<<dim3(100, 4, 4), 256, 0, stream>>>(FUSED, c1, MEAN, RSTD, rg, rb, PARTC);
    conv1_combine_kernel<<<(80000 + 255) / 256, 256, 0, stream>>>(PARTC, CB1);
    conv3x3_to4_kernel<true ><<<dim3(100, 8), 256, 0, stream>>>(CB1, c2, CB2);
    conv3x3_to4_kernel<true ><<<dim3(100, 8), 256, 0, stream>>>(CB2, c3, CB1);
    conv3x3_to4_kernel<false><<<dim3(100, 8), 256, 0, stream>>>(CB1, c4, CB2);
    rfm_out_kernel<<<100, 256, 0, stream>>>(CB2, FUSED, out);
}